// Round 1
// baseline (402.919 us; speedup 1.0000x reference)
//
#include <hip/hip_runtime.h>
#include <stdint.h>

#define T_ 4096
#define D_ 1024
#define F_ 4096
#define E_ 8
#define NCAT 8448  // 4096 (gate) + 4096 (up) + 256 (2*A1cat | 2*A3cat rows)

typedef __attribute__((ext_vector_type(8))) short          s16x8;
typedef __attribute__((ext_vector_type(8))) unsigned short u16x8;
typedef __attribute__((ext_vector_type(4))) float          f32x4;

__device__ __forceinline__ unsigned short f2bf(float f) {
  unsigned u = __float_as_uint(f);
  u += 0x7fffu + ((u >> 16) & 1u);   // round-to-nearest-even
  return (unsigned short)(u >> 16);
}
__device__ __forceinline__ float b2f(unsigned short h) {
  return __uint_as_float(((unsigned)h) << 16);
}

// ---------------------------------------------------------------- convert
__device__ __forceinline__ void cvt8(const float* __restrict__ s, unsigned short* __restrict__ d) {
  float4 a = *(const float4*)s;
  float4 b = *(const float4*)(s + 4);
  u16x8 v;
  v[0] = f2bf(a.x); v[1] = f2bf(a.y); v[2] = f2bf(a.z); v[3] = f2bf(a.w);
  v[4] = f2bf(b.x); v[5] = f2bf(b.y); v[6] = f2bf(b.z); v[7] = f2bf(b.w);
  *(u16x8*)d = v;
}

__global__ __launch_bounds__(256) void conv_kernel(
    const float* __restrict__ x,  const float* __restrict__ W1,
    const float* __restrict__ W3, const float* __restrict__ W2,
    const float* __restrict__ A1, const float* __restrict__ A3,
    const float* __restrict__ B1, const float* __restrict__ B3,
    const float* __restrict__ A2,
    unsigned short* __restrict__ xb,  unsigned short* __restrict__ Wcatb,
    unsigned short* __restrict__ W2b, unsigned short* __restrict__ B1b,
    unsigned short* __restrict__ B3b, unsigned short* __restrict__ A2t) {
  const int y = blockIdx.y;
  const size_t i0 = ((size_t)blockIdx.x * 256 + threadIdx.x) * 8;
  if (y == 0) { cvt8(x + i0, xb + i0); }
  else if (y == 1) { cvt8(W2 + i0, W2b + i0); }
  else if (y == 2) { cvt8(W1 + i0, Wcatb + i0); }
  else if (y == 3) { cvt8(W3 + i0, Wcatb + 4194304 + i0); }
  else {
    // small tensors, grid-stride scalar. SCALE=2 folded into A-matrices.
    for (size_t o = (size_t)blockIdx.x * 256 + threadIdx.x; o < 1835008; o += 524288) {
      if (o < 131072)        Wcatb[8388608 + o] = f2bf(2.f * A1[o]);
      else if (o < 262144)   Wcatb[8388608 + o] = f2bf(2.f * A3[o - 131072]);
      else if (o < 786432)   B1b[o - 262144]    = f2bf(B1[o - 262144]);
      else if (o < 1310720)  B3b[o - 786432]    = f2bf(B3[o - 786432]);
      else {
        size_t oo = o - 1310720;                 // A2t[e][f][r] = 2*A2[e][r][f]
        int e = (int)(oo >> 16), f = (int)((oo >> 4) & 4095), r = (int)(oo & 15);
        A2t[oo] = f2bf(2.f * A2[((size_t)e * 16 + r) * 4096 + f]);
      }
    }
  }
}

// ---------------------------------------------------------------- router
__global__ __launch_bounds__(256) void router_kernel(
    const float* __restrict__ x, const float* __restrict__ gw,
    float* __restrict__ logits, int2* __restrict__ topi, float2* __restrict__ topw) {
  const int wave = threadIdx.x >> 6, lane = threadIdx.x & 63;
  const int t = blockIdx.x * 4 + wave;
  const float* xr = x + (size_t)t * D_;
  float acc[E_] = {0, 0, 0, 0, 0, 0, 0, 0};
  for (int it = 0; it < 16; ++it) {
    const int d = lane + it * 64;
    const float xv = xr[d];
#pragma unroll
    for (int e = 0; e < E_; ++e) acc[e] += xv * gw[e * D_ + d];
  }
#pragma unroll
  for (int e = 0; e < E_; ++e)
#pragma unroll
    for (int m = 1; m < 64; m <<= 1) acc[e] += __shfl_xor(acc[e], m);
  if (lane == 0) {
    float m0v = acc[0]; int m0i = 0;
#pragma unroll
    for (int e = 1; e < E_; ++e) if (acc[e] > m0v) { m0v = acc[e]; m0i = e; }
    float m1v = -3.0e38f; int m1i = 0;
#pragma unroll
    for (int e = 0; e < E_; ++e) if (e != m0i && acc[e] > m1v) { m1v = acc[e]; m1i = e; }
    const float e1 = __expf(m1v - m0v);
    const float inv = 1.f / (1.f + e1);
    topi[t] = make_int2(m0i, m1i);
    topw[t] = make_float2(inv, e1 * inv);
#pragma unroll
    for (int e = 0; e < E_; ++e) logits[(size_t)t * E_ + e] = acc[e];
  }
}

// ---------------------------------------------------------------- GEMM: C[M,N] = A[M,K] @ B[N,K]^T   (bf16 in, f32/bf16 out)
__device__ __forceinline__ void cstore(float* C, size_t i, float v) { C[i] = v; }
__device__ __forceinline__ void cstore(unsigned short* C, size_t i, float v) { C[i] = f2bf(v); }

template <typename OUT_T>
__global__ __launch_bounds__(256) void gemm_bt(
    const unsigned short* __restrict__ A, const unsigned short* __restrict__ B,
    OUT_T* __restrict__ C, int M, int N, int K) {
  __shared__ __align__(16) char As[16384];  // 128 x 64 bf16, XOR-swizzled
  __shared__ __align__(16) char Bs[16384];
  const int tid = threadIdx.x;
  const long m0 = (long)blockIdx.x * 128, n0 = (long)blockIdx.y * 128;

  const unsigned short* ap[4];
  const unsigned short* bp[4];
  int sw[4];
#pragma unroll
  for (int i = 0; i < 4; ++i) {
    const int elem = i * 2048 + tid * 8;
    const int row = elem >> 6, col = elem & 63;
    ap[i] = A + (m0 + row) * (size_t)K + col;
    bp[i] = B + (n0 + row) * (size_t)K + col;
    sw[i] = (elem * 2) ^ ((row & 7) << 4);
  }
  const int lane = tid & 63, wave = tid >> 6;
  const int wr = wave >> 1, wc = wave & 1;
  int aoff[4][2], boff[4][2];
#pragma unroll
  for (int mf = 0; mf < 4; ++mf) {
    const int ra = wr * 64 + mf * 16 + (lane & 15);
    const int rb = wc * 64 + mf * 16 + (lane & 15);
#pragma unroll
    for (int ks = 0; ks < 2; ++ks) {
      const int kb = (ks * 32 + (lane >> 4) * 8) * 2;
      aoff[mf][ks] = (ra * 128 + kb) ^ ((ra & 7) << 4);
      boff[mf][ks] = (rb * 128 + kb) ^ ((rb & 7) << 4);
    }
  }
  f32x4 acc[4][4] = {};
  const int nk = K >> 6;
  for (int kt = 0; kt < nk; ++kt) {
    __syncthreads();
#pragma unroll
    for (int i = 0; i < 4; ++i) {
      u16x8 av = *(const u16x8*)ap[i]; ap[i] += 64;
      u16x8 bv = *(const u16x8*)bp[i]; bp[i] += 64;
      *(u16x8*)(As + sw[i]) = av;
      *(u16x8*)(Bs + sw[i]) = bv;
    }
    __syncthreads();
#pragma unroll
    for (int ks = 0; ks < 2; ++ks) {
      s16x8 af[4], bfv[4];
#pragma unroll
      for (int mf = 0; mf < 4; ++mf) af[mf] = *(const s16x8*)(As + aoff[mf][ks]);
#pragma unroll
      for (int nf = 0; nf < 4; ++nf) bfv[nf] = *(const s16x8*)(Bs + boff[nf][ks]);
#pragma unroll
      for (int mf = 0; mf < 4; ++mf)
#pragma unroll
        for (int nf = 0; nf < 4; ++nf)
          acc[mf][nf] = __builtin_amdgcn_mfma_f32_16x16x32_bf16(af[mf], bfv[nf], acc[mf][nf], 0, 0, 0);
    }
  }
#pragma unroll
  for (int mf = 0; mf < 4; ++mf) {
    const int row0 = (int)m0 + wr * 64 + mf * 16 + ((lane >> 4) << 2);
#pragma unroll
    for (int nf = 0; nf < 4; ++nf) {
      const long col = n0 + wc * 64 + nf * 16 + (lane & 15);
#pragma unroll
      for (int q = 0; q < 4; ++q)
        cstore(C, (size_t)(row0 + q) * N + col, acc[mf][nf][q]);
    }
  }
}

// ---------------------------------------------------------------- fused SwiGLU + LoRA (per-token top-2 only)
__global__ __launch_bounds__(256) void stage3_kernel(
    const unsigned short* __restrict__ xguP,  // [T, NCAT]
    const unsigned short* __restrict__ B1b,   // [E][F][16] bf16
    const unsigned short* __restrict__ B3b,   // [E][F][16] bf16
    const unsigned short* __restrict__ A2t,   // [E][F][16] bf16 (pre-scaled 2x)
    const int2* __restrict__ topi, const float2* __restrict__ topw,
    unsigned short* __restrict__ hsum,        // [T, F] bf16
    float* __restrict__ Qpart) {              // [64 strips][T][2][16]
  __shared__ __align__(16) char smem[49152];  // B1 | B3 | A2t : [e][f(64)][16] swizzled
  const int tid = threadIdx.x;
  const int t0 = blockIdx.x * 32, f0 = blockIdx.y * 64;

#pragma unroll
  for (int it = 0; it < 12; ++it) {
    const int c = it * 256 + tid;
    const int mat = c >> 10, cm = c & 1023;
    const int e = cm >> 7, ci = cm & 127;
    const int f = ci >> 1, s = ci & 1;
    const unsigned short* src = (mat == 0 ? B1b : (mat == 1 ? B3b : A2t)) +
                                ((size_t)e * F_ + f0 + f) * 16 + s * 8;
    const int dst = (mat << 14) + (e << 11) + (((f << 5) + (s << 4)) ^ ((f >> 3) << 4));
    *(u16x8*)(smem + dst) = *(const u16x8*)src;
  }
  __syncthreads();

  const int tl = tid >> 3, fc = tid & 7;
  const int t = t0 + tl;
  const unsigned short* xrow = xguP + (size_t)t * NCAT;
  float xg[8], xu[8];
  {
    u16x8 vg = *(const u16x8*)(xrow + f0 + fc * 8);
    u16x8 vu = *(const u16x8*)(xrow + 4096 + f0 + fc * 8);
#pragma unroll
    for (int j = 0; j < 8; ++j) { xg[j] = b2f(vg[j]); xu[j] = b2f(vu[j]); }
  }
  const int2 ti = topi[t];
  const float2 tw = topw[t];
  float hacc[8] = {0, 0, 0, 0, 0, 0, 0, 0};

#pragma unroll
  for (int k = 0; k < 2; ++k) {
    const int e = (k == 0) ? ti.x : ti.y;
    const float w = (k == 0) ? tw.x : tw.y;
    const unsigned short* pp = xrow + 8192 + e * 16;
    float p1[16], p3[16];
    {
      u16x8 a = *(const u16x8*)pp;
      u16x8 b = *(const u16x8*)(pp + 8);
      u16x8 c = *(const u16x8*)(pp + 128);
      u16x8 d = *(const u16x8*)(pp + 136);
#pragma unroll
      for (int r = 0; r < 8; ++r) {
        p1[r] = b2f(a[r]); p1[r + 8] = b2f(b[r]);
        p3[r] = b2f(c[r]); p3[r + 8] = b2f(d[r]);
      }
    }
    float q[16];
#pragma unroll
    for (int r = 0; r < 16; ++r) q[r] = 0.f;
    const int eb1 = (e << 11), eb3 = 16384 + (e << 11), ebA = 32768 + (e << 11);
#pragma unroll
    for (int j = 0; j < 8; ++j) {
      const int f = fc * 8 + j;
      const int o0 = (f << 5) ^ (fc << 4);
      const int o1 = ((f << 5) + 16) ^ (fc << 4);
      u16x8 b1l = *(const u16x8*)(smem + eb1 + o0);
      u16x8 b1h = *(const u16x8*)(smem + eb1 + o1);
      u16x8 b3l = *(const u16x8*)(smem + eb3 + o0);
      u16x8 b3h = *(const u16x8*)(smem + eb3 + o1);
      float lg = 0.f, lu = 0.f;
#pragma unroll
      for (int r = 0; r < 8; ++r) {
        lg += p1[r] * b2f(b1l[r]); lg += p1[r + 8] * b2f(b1h[r]);
        lu += p3[r] * b2f(b3l[r]); lu += p3[r + 8] * b2f(b3h[r]);
      }
      const float g = xg[j] + lg;
      const float u = xu[j] + lu;
      const float h = (g / (1.f + __expf(-g))) * u;
      const float hw = w * h;
      hacc[j] += hw;
      u16x8 a2l = *(const u16x8*)(smem + ebA + o0);
      u16x8 a2h = *(const u16x8*)(smem + ebA + o1);
#pragma unroll
      for (int r = 0; r < 8; ++r) { q[r] += hw * b2f(a2l[r]); q[r + 8] += hw * b2f(a2h[r]); }
    }
#pragma unroll
    for (int m = 1; m < 8; m <<= 1) {
#pragma unroll
      for (int r = 0; r < 16; ++r) q[r] += __shfl_xor(q[r], m);
    }
    if (fc == 0) {
      float* qp = Qpart + ((size_t)blockIdx.y * T_ + t) * 32 + k * 16;
#pragma unroll
      for (int r = 0; r < 16; ++r) qp[r] = q[r];
    }
  }
  u16x8 hv;
#pragma unroll
  for (int j = 0; j < 8; ++j) hv[j] = f2bf(hacc[j]);
  *(u16x8*)(hsum + (size_t)t * F_ + f0 + fc * 8) = hv;
}

// ---------------------------------------------------------------- strip reduce for q
__global__ __launch_bounds__(256) void qreduce_kernel(const float* __restrict__ Qpart,
                                                      float* __restrict__ Q) {
  const int o = blockIdx.x * 256 + threadIdx.x;  // 131072 total
  float s = 0.f;
  for (int st = 0; st < 64; ++st) s += Qpart[(size_t)st * 131072 + o];
  Q[o] = s;
}

// ---------------------------------------------------------------- down-LoRA epilogue: out += q @ B2^T
__global__ __launch_bounds__(256) void final_add_kernel(
    float* __restrict__ out, const float* __restrict__ Q,
    const int2* __restrict__ topi, const float* __restrict__ B2) {
  const int t = blockIdx.x, tid = threadIdx.x;
  const int2 ti = topi[t];
  float q0[16], q1[16];
#pragma unroll
  for (int r = 0; r < 16; ++r) { q0[r] = Q[(size_t)t * 32 + r]; q1[r] = Q[(size_t)t * 32 + 16 + r]; }
  const float* b2e0 = B2 + (size_t)ti.x * D_ * 16;
  const float* b2e1 = B2 + (size_t)ti.y * D_ * 16;
#pragma unroll
  for (int jj = 0; jj < 4; ++jj) {
    const int d = jj * 256 + tid;
    const float* r0 = b2e0 + (size_t)d * 16;
    const float* r1 = b2e1 + (size_t)d * 16;
    float acc = out[(size_t)t * D_ + d];
#pragma unroll
    for (int r = 0; r < 16; ++r) acc += q0[r] * r0[r] + q1[r] * r1[r];
    out[(size_t)t * D_ + d] = acc;
  }
}

// ---------------------------------------------------------------- launcher
extern "C" void kernel_launch(void* const* d_in, const int* in_sizes, int n_in,
                              void* d_out, int out_size, void* d_ws, size_t ws_size,
                              hipStream_t stream) {
  (void)in_sizes; (void)n_in; (void)out_size; (void)ws_size;
  const float* x   = (const float*)d_in[0];
  const float* gw  = (const float*)d_in[1];
  const float* W1  = (const float*)d_in[2];
  const float* W3  = (const float*)d_in[3];
  const float* W2  = (const float*)d_in[4];
  const float* A1  = (const float*)d_in[5];
  const float* B1  = (const float*)d_in[6];
  const float* A3  = (const float*)d_in[7];
  const float* B3  = (const float*)d_in[8];
  const float* A2  = (const float*)d_in[9];
  const float* B2  = (const float*)d_in[10];
  float* out = (float*)d_out;
  float* logits = out + (size_t)T_ * D_;

  char* w = (char*)d_ws;
  auto alloc = [&](size_t bytes) { char* p = w; w += (bytes + 255) & ~(size_t)255; return p; };
  unsigned short* xb    = (unsigned short*)alloc((size_t)T_ * D_ * 2);
  unsigned short* Wcatb = (unsigned short*)alloc((size_t)NCAT * D_ * 2);
  unsigned short* W2b   = (unsigned short*)alloc((size_t)D_ * F_ * 2);
  unsigned short* B1b   = (unsigned short*)alloc((size_t)E_ * F_ * 16 * 2);
  unsigned short* B3b   = (unsigned short*)alloc((size_t)E_ * F_ * 16 * 2);
  unsigned short* A2t   = (unsigned short*)alloc((size_t)E_ * F_ * 16 * 2);
  unsigned short* xguP  = (unsigned short*)alloc((size_t)T_ * NCAT * 2);
  unsigned short* hsum  = (unsigned short*)alloc((size_t)T_ * F_ * 2);
  float* Qpart          = (float*)alloc((size_t)64 * T_ * 32 * 4);
  float* Q              = (float*)alloc((size_t)T_ * 32 * 4);
  int2* topi            = (int2*)alloc((size_t)T_ * 8);
  float2* topw          = (float2*)alloc((size_t)T_ * 8);

  conv_kernel<<<dim3(2048, 5), 256, 0, stream>>>(x, W1, W3, W2, A1, A3, B1, B3, A2,
                                                 xb, Wcatb, W2b, B1b, B3b, A2t);
  router_kernel<<<dim3(1024), 256, 0, stream>>>(x, gw, logits, topi, topw);
  gemm_bt<unsigned short><<<dim3(32, 66), 256, 0, stream>>>(xb, Wcatb, xguP, T_, NCAT, D_);
  stage3_kernel<<<dim3(128, 64), 256, 0, stream>>>(xguP, B1b, B3b, A2t, topi, topw, hsum, Qpart);
  qreduce_kernel<<<dim3(512), 256, 0, stream>>>(Qpart, Q);
  gemm_bt<float><<<dim3(32, 8), 256, 0, stream>>>(hsum, W2b, out, T_, D_, F_);
  final_add_kernel<<<dim3(4096), 256, 0, stream>>>(out, Q, topi, B2);
}

// Round 3
// 402.839 us; speedup vs baseline: 1.0002x; 1.0002x over previous
//
#include <hip/hip_runtime.h>
#include <stdint.h>

#define T_ 4096
#define D_ 1024
#define F_ 4096
#define E_ 8
#define NCAT 8448  // 4096 (gate) + 4096 (up) + 256 (2*A1cat | 2*A3cat rows)

typedef __attribute__((ext_vector_type(8))) short          s16x8;
typedef __attribute__((ext_vector_type(8))) unsigned short u16x8;
typedef __attribute__((ext_vector_type(4))) float          f32x4;

__device__ __forceinline__ unsigned short f2bf(float f) {
  unsigned u = __float_as_uint(f);
  u += 0x7fffu + ((u >> 16) & 1u);   // round-to-nearest-even
  return (unsigned short)(u >> 16);
}
__device__ __forceinline__ float b2f(unsigned short h) {
  return __uint_as_float(((unsigned)h) << 16);
}
__device__ __forceinline__ float b2f_lo(unsigned v) { return __uint_as_float(v << 16); }
__device__ __forceinline__ float b2f_hi(unsigned v) { return __uint_as_float(v & 0xffff0000u); }
#define DW(v4, j) (((const unsigned*)&(v4))[j])

// ---------------------------------------------------------------- convert
__device__ __forceinline__ void cvt8(const float* __restrict__ s, unsigned short* __restrict__ d) {
  float4 a = *(const float4*)s;
  float4 b = *(const float4*)(s + 4);
  u16x8 v;
  v[0] = f2bf(a.x); v[1] = f2bf(a.y); v[2] = f2bf(a.z); v[3] = f2bf(a.w);
  v[4] = f2bf(b.x); v[5] = f2bf(b.y); v[6] = f2bf(b.z); v[7] = f2bf(b.w);
  *(u16x8*)d = v;
}

__global__ __launch_bounds__(256) void conv_kernel(
    const float* __restrict__ x,  const float* __restrict__ W1,
    const float* __restrict__ W3, const float* __restrict__ W2,
    const float* __restrict__ A1, const float* __restrict__ A3,
    const float* __restrict__ B1, const float* __restrict__ B3,
    const float* __restrict__ A2,
    unsigned short* __restrict__ xb,  unsigned short* __restrict__ Wcatb,
    unsigned short* __restrict__ W2b, unsigned short* __restrict__ B1b,
    unsigned short* __restrict__ B3b, unsigned short* __restrict__ A2r) {
  const int y = blockIdx.y;
  const size_t i0 = ((size_t)blockIdx.x * 256 + threadIdx.x) * 8;
  if (y == 0) { cvt8(x + i0, xb + i0); }
  else if (y == 1) { cvt8(W2 + i0, W2b + i0); }
  else if (y == 2) { cvt8(W1 + i0, Wcatb + i0); }
  else if (y == 3) { cvt8(W3 + i0, Wcatb + 4194304 + i0); }
  else {
    // small tensors, grid-stride scalar. SCALE=2 folded into A-matrices.
    for (size_t o = (size_t)blockIdx.x * 256 + threadIdx.x; o < 1835008; o += 524288) {
      if (o < 131072)        Wcatb[8388608 + o] = f2bf(2.f * A1[o]);
      else if (o < 262144)   Wcatb[8388608 + o] = f2bf(2.f * A3[o - 131072]);
      else if (o < 786432)   B1b[o - 262144]    = f2bf(B1[o - 262144]);
      else if (o < 1310720)  B3b[o - 786432]    = f2bf(B3[o - 786432]);
      else                   A2r[o - 1310720]   = f2bf(2.f * A2[o - 1310720]); // [E][16][F]
    }
  }
}

// ---------------------------------------------------------------- router
__global__ __launch_bounds__(256) void router_kernel(
    const float* __restrict__ x, const float* __restrict__ gw,
    float* __restrict__ logits, int2* __restrict__ topi, float2* __restrict__ topw) {
  const int wave = threadIdx.x >> 6, lane = threadIdx.x & 63;
  const int t = blockIdx.x * 4 + wave;
  const float* xr = x + (size_t)t * D_;
  float acc[E_] = {0, 0, 0, 0, 0, 0, 0, 0};
  for (int it = 0; it < 16; ++it) {
    const int d = lane + it * 64;
    const float xv = xr[d];
#pragma unroll
    for (int e = 0; e < E_; ++e) acc[e] += xv * gw[e * D_ + d];
  }
#pragma unroll
  for (int e = 0; e < E_; ++e)
#pragma unroll
    for (int m = 1; m < 64; m <<= 1) acc[e] += __shfl_xor(acc[e], m);
  if (lane == 0) {
    float m0v = acc[0]; int m0i = 0;
#pragma unroll
    for (int e = 1; e < E_; ++e) if (acc[e] > m0v) { m0v = acc[e]; m0i = e; }
    float m1v = -3.0e38f; int m1i = 0;
#pragma unroll
    for (int e = 0; e < E_; ++e) if (e != m0i && acc[e] > m1v) { m1v = acc[e]; m1i = e; }
    const float e1 = __expf(m1v - m0v);
    const float inv = 1.f / (1.f + e1);
    topi[t] = make_int2(m0i, m1i);
    topw[t] = make_float2(inv, e1 * inv);
#pragma unroll
    for (int e = 0; e < E_; ++e) logits[(size_t)t * E_ + e] = acc[e];
  }
}

// ---------------------------------------------------------------- pair buckets
__global__ __launch_bounds__(256) void bucket_kernel(
    const int2* __restrict__ topi, int* __restrict__ bucketTok, int* __restrict__ bucketCnt) {
  const int pid = blockIdx.x;
  const int e0 = pid >> 3, e1 = pid & 7;
  __shared__ int cnt;
  if (threadIdx.x == 0) cnt = 0;
  __syncthreads();
  for (int t = threadIdx.x; t < T_; t += 256) {
    const int2 ti = topi[t];
    if (ti.x == e0 && ti.y == e1) {
      const int s = atomicAdd(&cnt, 1);
      bucketTok[pid * T_ + s] = t;
    }
  }
  __syncthreads();
  if (threadIdx.x == 0) bucketCnt[pid] = cnt;
}

// ---------------------------------------------------------------- GEMM: C[M,N] = A[M,K] @ B[N,K]^T
__device__ __forceinline__ void cstore(float* C, size_t i, float v) { C[i] = v; }
__device__ __forceinline__ void cstore(unsigned short* C, size_t i, float v) { C[i] = f2bf(v); }

#define GLL(g, l) __builtin_amdgcn_global_load_lds(                            \
    (const __attribute__((address_space(1))) void*)(g),                       \
    (__attribute__((address_space(3))) void*)(l), 16, 0, 0)

template <int BN, typename OUT_T>
__global__ __launch_bounds__(256) void gemm_bt(
    const unsigned short* __restrict__ A, const unsigned short* __restrict__ B,
    OUT_T* __restrict__ C, int M, int N, int K, int nbx) {
  constexpr int WCOL = BN / 2, NF = WCOL / 16;
  constexpr int BITER = BN / 32;                 // 16B granules per thread for B tile
  __shared__ __align__(16) char As[16384];       // 128 x 64 bf16, XOR-swizzled image
  __shared__ __align__(16) char Bs[BN * 128];
  const int tid = threadIdx.x;
  int bid = blockIdx.x;
  bid = (bid & 7) * (gridDim.x >> 3) + (bid >> 3);  // XCD swizzle (grid %8==0)
  const int bx = bid % nbx, by = bid / nbx;
  const long m0 = (long)bx * 128, n0 = (long)by * BN;

  // pre-swizzled global sources: linear LDS granule g holds source (row=g>>3, cb=(g&7)^(row&7))
  const unsigned short* asrc[4];
  const unsigned short* bsrc[BITER];
#pragma unroll
  for (int i = 0; i < 4; ++i) {
    const int g = i * 256 + tid, row = g >> 3, cb = (g & 7) ^ (row & 7);
    asrc[i] = A + (m0 + row) * (size_t)K + cb * 8;
  }
#pragma unroll
  for (int i = 0; i < BITER; ++i) {
    const int g = i * 256 + tid, row = g >> 3, cb = (g & 7) ^ (row & 7);
    bsrc[i] = B + (n0 + row) * (size_t)K + cb * 8;
  }
  const int lane = tid & 63, wave = tid >> 6;
  const int wr = wave >> 1, wc = wave & 1;
  const int wb = (tid & 192) * 16;               // wave-uniform LDS granule base (bytes)
  int aoff[4][2], boff[NF][2];
#pragma unroll
  for (int mf = 0; mf < 4; ++mf) {
    const int ra = wr * 64 + mf * 16 + (lane & 15);
#pragma unroll
    for (int ks = 0; ks < 2; ++ks) {
      const int kb = (ks * 32 + (lane >> 4) * 8) * 2;
      aoff[mf][ks] = (ra * 128 + kb) ^ ((ra & 7) << 4);
    }
  }
#pragma unroll
  for (int nf = 0; nf < NF; ++nf) {
    const int rb = wc * WCOL + nf * 16 + (lane & 15);
#pragma unroll
    for (int ks = 0; ks < 2; ++ks) {
      const int kb = (ks * 32 + (lane >> 4) * 8) * 2;
      boff[nf][ks] = (rb * 128 + kb) ^ ((rb & 7) << 4);
    }
  }
  f32x4 acc[4][NF] = {};
  const int nk = K >> 6;
  for (int kt = 0; kt < nk; ++kt) {
    __syncthreads();
#pragma unroll
    for (int i = 0; i < 4; ++i) {
      GLL(asrc[i], As + i * 4096 + wb);
      asrc[i] += 64;
    }
#pragma unroll
    for (int i = 0; i < BITER; ++i) {
      GLL(bsrc[i], Bs + i * 4096 + wb);
      bsrc[i] += 64;
    }
    __syncthreads();
#pragma unroll
    for (int ks = 0; ks < 2; ++ks) {
      s16x8 af[4], bfv[NF];
#pragma unroll
      for (int mf = 0; mf < 4; ++mf) af[mf] = *(const s16x8*)(As + aoff[mf][ks]);
#pragma unroll
      for (int nf = 0; nf < NF; ++nf) bfv[nf] = *(const s16x8*)(Bs + boff[nf][ks]);
#pragma unroll
      for (int mf = 0; mf < 4; ++mf)
#pragma unroll
        for (int nf = 0; nf < NF; ++nf)
          acc[mf][nf] = __builtin_amdgcn_mfma_f32_16x16x32_bf16(af[mf], bfv[nf], acc[mf][nf], 0, 0, 0);
    }
  }
#pragma unroll
  for (int mf = 0; mf < 4; ++mf) {
    const int row0 = (int)m0 + wr * 64 + mf * 16 + ((lane >> 4) << 2);
#pragma unroll
    for (int nf = 0; nf < NF; ++nf) {
      const long col = n0 + wc * WCOL + nf * 16 + (lane & 15);
#pragma unroll
      for (int q = 0; q < 4; ++q)
        cstore(C, (size_t)(row0 + q) * N + col, acc[mf][nf][q]);
    }
  }
}

// ---------------------------------------------------------------- fused SwiGLU + LoRA-B (pair-grouped, register-B, scalar f32 math)
__global__ __launch_bounds__(256) void s3a_kernel(
    const unsigned short* __restrict__ xguP,  // [T, NCAT]
    const unsigned short* __restrict__ B1b,   // [E][F][16] bf16
    const unsigned short* __restrict__ B3b,   // [E][F][16] bf16
    const int* __restrict__ bucketTok, const int* __restrict__ bucketCnt,
    const float2* __restrict__ topw,
    unsigned short* __restrict__ hk,          // [2][T][F] bf16 (w_k * h_k)
    unsigned short* __restrict__ hsum) {      // [T][F] bf16
  const int pid = blockIdx.y;
  const int nt = bucketCnt[pid];
  if (nt == 0) return;
  const int e0 = pid >> 3, e1 = pid & 7;
  const int f = blockIdx.x * 256 + threadIdx.x;   // one feature per thread

  // B rows for feature f, both experts: 16 bf16 each = 8 packed pairs
  unsigned B1r[2][8], B3r[2][8];
#pragma unroll
  for (int ke = 0; ke < 2; ++ke) {
    const int e = ke ? e1 : e0;
    const uint4* p1 = (const uint4*)(B1b + ((size_t)e * F_ + f) * 16);
    const uint4* p3 = (const uint4*)(B3b + ((size_t)e * F_ + f) * 16);
    *(uint4*)&B1r[ke][0] = p1[0]; *(uint4*)&B1r[ke][4] = p1[1];
    *(uint4*)&B3r[ke][0] = p3[0]; *(uint4*)&B3r[ke][4] = p3[1];
  }

  for (int i = 0; i < nt; ++i) {
    const int t = bucketTok[pid * T_ + i];
    const float2 w = topw[t];
    const unsigned short* xrow = xguP + (size_t)t * NCAT;
    const float xgf = b2f(xrow[f]);
    const float xuf = b2f(xrow[4096 + f]);
    float hw[2];
#pragma unroll
    for (int k = 0; k < 2; ++k) {
      const int e = k ? e1 : e0;
      const float wk = k ? w.y : w.x;
      const unsigned short* pr = xrow + 8192 + e * 16;
      uint4 pa = *(const uint4*)pr;          // p1 ranks 0-7
      uint4 pb = *(const uint4*)(pr + 8);    // p1 ranks 8-15
      uint4 pc = *(const uint4*)(pr + 128);  // p3 ranks 0-7
      uint4 pd = *(const uint4*)(pr + 136);  // p3 ranks 8-15
      float lg = 0.f, lu = 0.f;
#pragma unroll
      for (int r = 0; r < 4; ++r) {
        const unsigned va = DW(pa, r), vb = DW(pb, r), vc = DW(pc, r), vd = DW(pd, r);
        lg += b2f_lo(va) * b2f_lo(B1r[k][r]);
        lg += b2f_hi(va) * b2f_hi(B1r[k][r]);
        lg += b2f_lo(vb) * b2f_lo(B1r[k][4 + r]);
        lg += b2f_hi(vb) * b2f_hi(B1r[k][4 + r]);
        lu += b2f_lo(vc) * b2f_lo(B3r[k][r]);
        lu += b2f_hi(vc) * b2f_hi(B3r[k][r]);
        lu += b2f_lo(vd) * b2f_lo(B3r[k][4 + r]);
        lu += b2f_hi(vd) * b2f_hi(B3r[k][4 + r]);
      }
      const float g = xgf + lg;
      const float u = xuf + lu;
      const float h = (g / (1.f + __expf(-g))) * u;   // exact round-1 silu
      hw[k] = wk * h;
    }
    hk[(size_t)t * F_ + f]                   = f2bf(hw[0]);
    hk[(size_t)T_ * F_ + (size_t)t * F_ + f] = f2bf(hw[1]);
    hsum[(size_t)t * F_ + f]                 = f2bf(hw[0] + hw[1]);
  }
}

// ---------------------------------------------------------------- q = hw_k @ (2*A2[e])^T  via gather-MFMA
__global__ __launch_bounds__(256) void qgemm_kernel(
    const unsigned short* __restrict__ hk, const unsigned short* __restrict__ A2r,
    const int* __restrict__ bucketTok, const int* __restrict__ bucketCnt,
    float* __restrict__ Q) {                  // [T][32]
  const int pid = blockIdx.x, k = blockIdx.y;
  const int nt = bucketCnt[pid];
  if (nt == 0) return;
  const int e = k ? (pid & 7) : (pid >> 3);
  const int lane = threadIdx.x & 63, wave = threadIdx.x >> 6;
  const int rc = lane & 15, kseg = lane >> 4;
  const unsigned short* brow = A2r + ((size_t)e * 16 + rc) * F_ + kseg * 8;
  const unsigned short* hbase = hk + (size_t)k * T_ * F_;
  const int ntile = (nt + 15) >> 4;
  for (int tile = wave; tile < ntile; tile += 4) {
    const int sA = tile * 16 + rc;
    const int tA = bucketTok[pid * T_ + (sA < nt ? sA : nt - 1)];
    const unsigned short* arow = hbase + (size_t)tA * F_ + kseg * 8;
    f32x4 acc = {};
#pragma unroll 4
    for (int fo = 0; fo < F_; fo += 32) {
      s16x8 av = *(const s16x8*)(arow + fo);
      s16x8 bv = *(const s16x8*)(brow + fo);
      acc = __builtin_amdgcn_mfma_f32_16x16x32_bf16(av, bv, acc, 0, 0, 0);
    }
#pragma unroll
    for (int qi = 0; qi < 4; ++qi) {
      const int s = tile * 16 + kseg * 4 + qi;
      if (s < nt) {
        const int tC = bucketTok[pid * T_ + s];
        Q[(size_t)tC * 32 + k * 16 + rc] = acc[qi];
      }
    }
  }
}

// ---------------------------------------------------------------- down-LoRA epilogue: out += q @ B2^T
__global__ __launch_bounds__(256) void final_add_kernel(
    float* __restrict__ out, const float* __restrict__ Q,
    const int2* __restrict__ topi, const float* __restrict__ B2) {
  const int t = blockIdx.x, tid = threadIdx.x;
  const int2 ti = topi[t];
  float q0[16], q1[16];
#pragma unroll
  for (int r = 0; r < 16; ++r) { q0[r] = Q[(size_t)t * 32 + r]; q1[r] = Q[(size_t)t * 32 + 16 + r]; }
  const float* b2e0 = B2 + (size_t)ti.x * D_ * 16;
  const float* b2e1 = B2 + (size_t)ti.y * D_ * 16;
#pragma unroll
  for (int jj = 0; jj < 4; ++jj) {
    const int d = jj * 256 + tid;
    const float* r0 = b2e0 + (size_t)d * 16;
    const float* r1 = b2e1 + (size_t)d * 16;
    float acc = out[(size_t)t * D_ + d];
#pragma unroll
    for (int r = 0; r < 16; ++r) acc += q0[r] * r0[r] + q1[r] * r1[r];
    out[(size_t)t * D_ + d] = acc;
  }
}

// ---------------------------------------------------------------- launcher
extern "C" void kernel_launch(void* const* d_in, const int* in_sizes, int n_in,
                              void* d_out, int out_size, void* d_ws, size_t ws_size,
                              hipStream_t stream) {
  (void)in_sizes; (void)n_in; (void)out_size; (void)ws_size;
  const float* x   = (const float*)d_in[0];
  const float* gw  = (const float*)d_in[1];
  const float* W1  = (const float*)d_in[2];
  const float* W3  = (const float*)d_in[3];
  const float* W2  = (const float*)d_in[4];
  const float* A1  = (const float*)d_in[5];
  const float* B1  = (const float*)d_in[6];
  const float* A3  = (const float*)d_in[7];
  const float* B3  = (const float*)d_in[8];
  const float* A2  = (const float*)d_in[9];
  const float* B2  = (const float*)d_in[10];
  float* out = (float*)d_out;
  float* logits = out + (size_t)T_ * D_;

  char* w = (char*)d_ws;
  auto alloc = [&](size_t bytes) { char* p = w; w += (bytes + 255) & ~(size_t)255; return p; };
  unsigned short* xb    = (unsigned short*)alloc((size_t)T_ * D_ * 2);
  unsigned short* Wcatb = (unsigned short*)alloc((size_t)NCAT * D_ * 2);
  unsigned short* W2b   = (unsigned short*)alloc((size_t)D_ * F_ * 2);
  unsigned short* B1b   = (unsigned short*)alloc((size_t)E_ * F_ * 16 * 2);
  unsigned short* B3b   = (unsigned short*)alloc((size_t)E_ * F_ * 16 * 2);
  unsigned short* A2r   = (unsigned short*)alloc((size_t)E_ * 16 * F_ * 2);
  unsigned short* xguP  = (unsigned short*)alloc((size_t)T_ * NCAT * 2);
  unsigned short* hsum  = (unsigned short*)alloc((size_t)T_ * F_ * 2);
  unsigned short* hk    = (unsigned short*)alloc((size_t)2 * T_ * F_ * 2);
  float* Q              = (float*)alloc((size_t)T_ * 32 * 4);
  int* bucketTok        = (int*)alloc((size_t)64 * T_ * 4);
  int* bucketCnt        = (int*)alloc((size_t)64 * 4);
  int2* topi            = (int2*)alloc((size_t)T_ * 8);
  float2* topw          = (float2*)alloc((size_t)T_ * 8);

  conv_kernel<<<dim3(2048, 5), 256, 0, stream>>>(x, W1, W3, W2, A1, A3, B1, B3, A2,
                                                 xb, Wcatb, W2b, B1b, B3b, A2r);
  router_kernel<<<dim3(1024), 256, 0, stream>>>(x, gw, logits, topi, topw);
  bucket_kernel<<<dim3(64), 256, 0, stream>>>(topi, bucketTok, bucketCnt);
  gemm_bt<128, unsigned short><<<dim3(32 * 66), 256, 0, stream>>>(xb, Wcatb, xguP, T_, NCAT, D_, 32);
  s3a_kernel<<<dim3(16, 64), 256, 0, stream>>>(xguP, B1b, B3b, bucketTok, bucketCnt, topw, hk, hsum);
  qgemm_kernel<<<dim3(64, 2), 256, 0, stream>>>(hk, A2r, bucketTok, bucketCnt, Q);
  gemm_bt<64, float><<<dim3(32 * 16), 256, 0, stream>>>(hsum, W2b, out, T_, D_, F_, 32);
  final_add_kernel<<<dim3(4096), 256, 0, stream>>>(out, Q, topi, B2);
}

// Round 4
// 373.152 us; speedup vs baseline: 1.0798x; 1.0796x over previous
//
#include <hip/hip_runtime.h>
#include <stdint.h>

#define T_ 4096
#define D_ 1024
#define F_ 4096
#define E_ 8
#define NCAT 8448  // 4096 (gate) + 4096 (up) + 256 (2*A1cat | 2*A3cat rows)

typedef __attribute__((ext_vector_type(8))) short          s16x8;
typedef __attribute__((ext_vector_type(8))) unsigned short u16x8;
typedef __attribute__((ext_vector_type(4))) float          f32x4;

__device__ __forceinline__ unsigned short f2bf(float f) {
  unsigned u = __float_as_uint(f);
  u += 0x7fffu + ((u >> 16) & 1u);   // round-to-nearest-even
  return (unsigned short)(u >> 16);
}
__device__ __forceinline__ float b2f(unsigned short h) {
  return __uint_as_float(((unsigned)h) << 16);
}
__device__ __forceinline__ float b2f_lo(unsigned v) { return __uint_as_float(v << 16); }
__device__ __forceinline__ float b2f_hi(unsigned v) { return __uint_as_float(v & 0xffff0000u); }
#define DW(v4, j) (((const unsigned*)&(v4))[j])

// ---------------------------------------------------------------- convert
__device__ __forceinline__ void cvt8(const float* __restrict__ s, unsigned short* __restrict__ d) {
  float4 a = *(const float4*)s;
  float4 b = *(const float4*)(s + 4);
  u16x8 v;
  v[0] = f2bf(a.x); v[1] = f2bf(a.y); v[2] = f2bf(a.z); v[3] = f2bf(a.w);
  v[4] = f2bf(b.x); v[5] = f2bf(b.y); v[6] = f2bf(b.z); v[7] = f2bf(b.w);
  *(u16x8*)d = v;
}

__global__ __launch_bounds__(256) void conv_kernel(
    const float* __restrict__ x,  const float* __restrict__ W1,
    const float* __restrict__ W3, const float* __restrict__ W2,
    const float* __restrict__ A1, const float* __restrict__ A3,
    const float* __restrict__ B1, const float* __restrict__ B3,
    const float* __restrict__ A2,
    unsigned short* __restrict__ xb,  unsigned short* __restrict__ Wcatb,
    unsigned short* __restrict__ W2b, unsigned short* __restrict__ B1b,
    unsigned short* __restrict__ B3b, unsigned short* __restrict__ A2r) {
  const int y = blockIdx.y;
  const size_t i0 = ((size_t)blockIdx.x * 256 + threadIdx.x) * 8;
  if (y == 0) { cvt8(x + i0, xb + i0); }
  else if (y == 1) { cvt8(W2 + i0, W2b + i0); }
  else if (y == 2) { cvt8(W1 + i0, Wcatb + i0); }
  else if (y == 3) { cvt8(W3 + i0, Wcatb + 4194304 + i0); }
  else {
    // small tensors, grid-stride scalar. SCALE=2 folded into A-matrices.
    for (size_t o = (size_t)blockIdx.x * 256 + threadIdx.x; o < 1835008; o += 524288) {
      if (o < 131072)        Wcatb[8388608 + o] = f2bf(2.f * A1[o]);
      else if (o < 262144)   Wcatb[8388608 + o] = f2bf(2.f * A3[o - 131072]);
      else if (o < 786432)   B1b[o - 262144]    = f2bf(B1[o - 262144]);
      else if (o < 1310720)  B3b[o - 786432]    = f2bf(B3[o - 786432]);
      else                   A2r[o - 1310720]   = f2bf(2.f * A2[o - 1310720]); // [E][16][F]
    }
  }
}

// ---------------------------------------------------------------- router
__global__ __launch_bounds__(256) void router_kernel(
    const float* __restrict__ x, const float* __restrict__ gw,
    float* __restrict__ logits, int2* __restrict__ topi, float2* __restrict__ topw) {
  const int wave = threadIdx.x >> 6, lane = threadIdx.x & 63;
  const int t = blockIdx.x * 4 + wave;
  const float* xr = x + (size_t)t * D_;
  float acc[E_] = {0, 0, 0, 0, 0, 0, 0, 0};
  for (int it = 0; it < 16; ++it) {
    const int d = lane + it * 64;
    const float xv = xr[d];
#pragma unroll
    for (int e = 0; e < E_; ++e) acc[e] += xv * gw[e * D_ + d];
  }
#pragma unroll
  for (int e = 0; e < E_; ++e)
#pragma unroll
    for (int m = 1; m < 64; m <<= 1) acc[e] += __shfl_xor(acc[e], m);
  if (lane == 0) {
    float m0v = acc[0]; int m0i = 0;
#pragma unroll
    for (int e = 1; e < E_; ++e) if (acc[e] > m0v) { m0v = acc[e]; m0i = e; }
    float m1v = -3.0e38f; int m1i = 0;
#pragma unroll
    for (int e = 0; e < E_; ++e) if (e != m0i && acc[e] > m1v) { m1v = acc[e]; m1i = e; }
    const float e1 = __expf(m1v - m0v);
    const float inv = 1.f / (1.f + e1);
    topi[t] = make_int2(m0i, m1i);
    topw[t] = make_float2(inv, e1 * inv);
#pragma unroll
    for (int e = 0; e < E_; ++e) logits[(size_t)t * E_ + e] = acc[e];
  }
}

// ---------------------------------------------------------------- pair buckets
__global__ __launch_bounds__(256) void bucket_kernel(
    const int2* __restrict__ topi, int* __restrict__ bucketTok, int* __restrict__ bucketCnt) {
  const int pid = blockIdx.x;
  const int e0 = pid >> 3, e1 = pid & 7;
  __shared__ int cnt;
  if (threadIdx.x == 0) cnt = 0;
  __syncthreads();
  for (int t = threadIdx.x; t < T_; t += 256) {
    const int2 ti = topi[t];
    if (ti.x == e0 && ti.y == e1) {
      const int s = atomicAdd(&cnt, 1);
      bucketTok[pid * T_ + s] = t;
    }
  }
  __syncthreads();
  if (threadIdx.x == 0) bucketCnt[pid] = cnt;
}

// ---------------------------------------------------------------- GEMM: C[M,N] = A[M,K] @ B[N,K]^T
__device__ __forceinline__ void cstore(float* C, size_t i, float v) { C[i] = v; }
__device__ __forceinline__ void cstore(unsigned short* C, size_t i, float v) { C[i] = f2bf(v); }

#define GLL(g, l) __builtin_amdgcn_global_load_lds(                            \
    (const __attribute__((address_space(1))) void*)(g),                       \
    (__attribute__((address_space(3))) void*)(l), 16, 0, 0)

template <int BN, typename OUT_T>
__global__ __launch_bounds__(256) void gemm_bt(
    const unsigned short* __restrict__ A, const unsigned short* __restrict__ B,
    OUT_T* __restrict__ C, int M, int N, int K, int nbx) {
  constexpr int WCOL = BN / 2, NF = WCOL / 16;
  constexpr int BITER = BN / 32;                 // 16B granules per thread for B tile
  __shared__ __align__(16) char As[16384];       // 128 x 64 bf16, XOR-swizzled image
  __shared__ __align__(16) char Bs[BN * 128];
  const int tid = threadIdx.x;
  int bid = blockIdx.x;
  bid = (bid & 7) * (gridDim.x >> 3) + (bid >> 3);  // XCD swizzle (grid %8==0)
  const int bx = bid % nbx, by = bid / nbx;
  const long m0 = (long)bx * 128, n0 = (long)by * BN;

  // pre-swizzled global sources: linear LDS granule g holds source (row=g>>3, cb=(g&7)^(row&7))
  const unsigned short* asrc[4];
  const unsigned short* bsrc[BITER];
#pragma unroll
  for (int i = 0; i < 4; ++i) {
    const int g = i * 256 + tid, row = g >> 3, cb = (g & 7) ^ (row & 7);
    asrc[i] = A + (m0 + row) * (size_t)K + cb * 8;
  }
#pragma unroll
  for (int i = 0; i < BITER; ++i) {
    const int g = i * 256 + tid, row = g >> 3, cb = (g & 7) ^ (row & 7);
    bsrc[i] = B + (n0 + row) * (size_t)K + cb * 8;
  }
  const int lane = tid & 63, wave = tid >> 6;
  const int wr = wave >> 1, wc = wave & 1;
  const int wb = (tid & 192) * 16;               // wave-uniform LDS granule base (bytes)
  int aoff[4][2], boff[NF][2];
#pragma unroll
  for (int mf = 0; mf < 4; ++mf) {
    const int ra = wr * 64 + mf * 16 + (lane & 15);
#pragma unroll
    for (int ks = 0; ks < 2; ++ks) {
      const int kb = (ks * 32 + (lane >> 4) * 8) * 2;
      aoff[mf][ks] = (ra * 128 + kb) ^ ((ra & 7) << 4);
    }
  }
#pragma unroll
  for (int nf = 0; nf < NF; ++nf) {
    const int rb = wc * WCOL + nf * 16 + (lane & 15);
#pragma unroll
    for (int ks = 0; ks < 2; ++ks) {
      const int kb = (ks * 32 + (lane >> 4) * 8) * 2;
      boff[nf][ks] = (rb * 128 + kb) ^ ((rb & 7) << 4);
    }
  }
  f32x4 acc[4][NF] = {};
  const int nk = K >> 6;
  for (int kt = 0; kt < nk; ++kt) {
    __syncthreads();
#pragma unroll
    for (int i = 0; i < 4; ++i) {
      GLL(asrc[i], As + i * 4096 + wb);
      asrc[i] += 64;
    }
#pragma unroll
    for (int i = 0; i < BITER; ++i) {
      GLL(bsrc[i], Bs + i * 4096 + wb);
      bsrc[i] += 64;
    }
    __syncthreads();
#pragma unroll
    for (int ks = 0; ks < 2; ++ks) {
      s16x8 af[4], bfv[NF];
#pragma unroll
      for (int mf = 0; mf < 4; ++mf) af[mf] = *(const s16x8*)(As + aoff[mf][ks]);
#pragma unroll
      for (int nf = 0; nf < NF; ++nf) bfv[nf] = *(const s16x8*)(Bs + boff[nf][ks]);
#pragma unroll
      for (int mf = 0; mf < 4; ++mf)
#pragma unroll
        for (int nf = 0; nf < NF; ++nf)
          acc[mf][nf] = __builtin_amdgcn_mfma_f32_16x16x32_bf16(af[mf], bfv[nf], acc[mf][nf], 0, 0, 0);
    }
  }
#pragma unroll
  for (int mf = 0; mf < 4; ++mf) {
    const int row0 = (int)m0 + wr * 64 + mf * 16 + ((lane >> 4) << 2);
#pragma unroll
    for (int nf = 0; nf < NF; ++nf) {
      const long col = n0 + wc * WCOL + nf * 16 + (lane & 15);
#pragma unroll
      for (int q = 0; q < 4; ++q)
        cstore(C, (size_t)(row0 + q) * N + col, acc[mf][nf][q]);
    }
  }
}

// ---------------------------------------------------------------- fused SwiGLU + LoRA-B
// pair-grouped, register-B, scalar f32 math (validated round 3), token-interleaved z + prefetch
#define S3A_NZ 8
__global__ __launch_bounds__(256) void s3a_kernel(
    const unsigned short* __restrict__ xguP,  // [T, NCAT]
    const unsigned short* __restrict__ B1b,   // [E][F][16] bf16
    const unsigned short* __restrict__ B3b,   // [E][F][16] bf16
    const int* __restrict__ bucketTok, const int* __restrict__ bucketCnt,
    const float2* __restrict__ topw,
    unsigned short* __restrict__ hk,          // [2][T][F] bf16 (w_k * h_k)
    unsigned short* __restrict__ hsum) {      // [T][F] bf16
  const int pid = blockIdx.y;
  const int nt = bucketCnt[pid];
  const int z = blockIdx.z;
  if (z >= nt) return;
  const int e0 = pid >> 3, e1 = pid & 7;
  const int f = blockIdx.x * 256 + threadIdx.x;   // one feature per thread

  // B rows for feature f, both experts: 16 bf16 each = 8 packed pairs
  unsigned B1r[2][8], B3r[2][8];
#pragma unroll
  for (int ke = 0; ke < 2; ++ke) {
    const int e = ke ? e1 : e0;
    const uint4* p1 = (const uint4*)(B1b + ((size_t)e * F_ + f) * 16);
    const uint4* p3 = (const uint4*)(B3b + ((size_t)e * F_ + f) * 16);
    *(uint4*)&B1r[ke][0] = p1[0]; *(uint4*)&B1r[ke][4] = p1[1];
    *(uint4*)&B3r[ke][0] = p3[0]; *(uint4*)&B3r[ke][4] = p3[1];
  }

  auto LOADTOK = [&](int i, int& t, float2& w, uint4 (&pv)[8], float& xgf, float& xuf) {
    t = bucketTok[pid * T_ + i];
    w = topw[t];
    const unsigned short* xrow = xguP + (size_t)t * NCAT;
    const unsigned short* pr = xrow + 8192;
    pv[0] = *(const uint4*)(pr + e0 * 16);        // p1 e0 ranks 0-7
    pv[1] = *(const uint4*)(pr + e0 * 16 + 8);    // p1 e0 ranks 8-15
    pv[2] = *(const uint4*)(pr + 128 + e0 * 16);  // p3 e0
    pv[3] = *(const uint4*)(pr + 128 + e0 * 16 + 8);
    pv[4] = *(const uint4*)(pr + e1 * 16);        // p1 e1
    pv[5] = *(const uint4*)(pr + e1 * 16 + 8);
    pv[6] = *(const uint4*)(pr + 128 + e1 * 16);  // p3 e1
    pv[7] = *(const uint4*)(pr + 128 + e1 * 16 + 8);
    xgf = b2f(xrow[f]);
    xuf = b2f(xrow[4096 + f]);
  };

  auto COMPUTE = [&](int t, float2 w, uint4 (&pv)[8], float xgf, float xuf) {
    float hw[2];
#pragma unroll
    for (int k = 0; k < 2; ++k) {
      const float wk = k ? w.y : w.x;
      const uint4& pa = pv[k * 4 + 0];
      const uint4& pb = pv[k * 4 + 1];
      const uint4& pc = pv[k * 4 + 2];
      const uint4& pd = pv[k * 4 + 3];
      float lg = 0.f, lu = 0.f;
#pragma unroll
      for (int r = 0; r < 4; ++r) {
        const unsigned va = DW(pa, r), vb = DW(pb, r), vc = DW(pc, r), vd = DW(pd, r);
        lg += b2f_lo(va) * b2f_lo(B1r[k][r]);
        lg += b2f_hi(va) * b2f_hi(B1r[k][r]);
        lg += b2f_lo(vb) * b2f_lo(B1r[k][4 + r]);
        lg += b2f_hi(vb) * b2f_hi(B1r[k][4 + r]);
        lu += b2f_lo(vc) * b2f_lo(B3r[k][r]);
        lu += b2f_hi(vc) * b2f_hi(B3r[k][r]);
        lu += b2f_lo(vd) * b2f_lo(B3r[k][4 + r]);
        lu += b2f_hi(vd) * b2f_hi(B3r[k][4 + r]);
      }
      const float g = xgf + lg;
      const float u = xuf + lu;
      const float h = (g / (1.f + __expf(-g))) * u;   // exact round-1 silu
      hw[k] = wk * h;
    }
    hk[(size_t)t * F_ + f]                   = f2bf(hw[0]);
    hk[(size_t)T_ * F_ + (size_t)t * F_ + f] = f2bf(hw[1]);
    hsum[(size_t)t * F_ + f]                 = f2bf(hw[0] + hw[1]);
  };

  int tA; float2 wA; uint4 pA[8]; float xgA, xuA;
  int tB; float2 wB; uint4 pB[8]; float xgB, xuB;
  LOADTOK(z, tA, wA, pA, xgA, xuA);
  for (int i = z; i < nt; i += 2 * S3A_NZ) {
    if (i + S3A_NZ < nt)     LOADTOK(i + S3A_NZ, tB, wB, pB, xgB, xuB);
    COMPUTE(tA, wA, pA, xgA, xuA);
    if (i + 2 * S3A_NZ < nt) LOADTOK(i + 2 * S3A_NZ, tA, wA, pA, xgA, xuA);
    if (i + S3A_NZ < nt)     COMPUTE(tB, wB, pB, xgB, xuB);
  }
}

// ---------------------------------------------------------------- q = hw_k @ (2*A2[e])^T  via gather-MFMA, F split 4-way
__global__ __launch_bounds__(256) void qgemm_kernel(
    const unsigned short* __restrict__ hk, const unsigned short* __restrict__ A2r,
    const int* __restrict__ bucketTok, const int* __restrict__ bucketCnt,
    float* __restrict__ Qpart) {              // [4][T][32]
  const int pid = blockIdx.x, k = blockIdx.y, zf = blockIdx.z;
  const int nt = bucketCnt[pid];
  if (nt == 0) return;
  const int e = k ? (pid & 7) : (pid >> 3);
  const int lane = threadIdx.x & 63, wave = threadIdx.x >> 6;
  const int rc = lane & 15, kseg = lane >> 4;
  const int f0 = zf * 1024;
  const unsigned short* brow = A2r + ((size_t)e * 16 + rc) * F_ + f0 + kseg * 8;
  const unsigned short* hbase = hk + (size_t)k * T_ * F_ + f0;
  const int ntile = (nt + 15) >> 4;
  for (int tile = wave; tile < ntile; tile += 4) {
    const int sA = tile * 16 + rc;
    const int tA = bucketTok[pid * T_ + (sA < nt ? sA : nt - 1)];
    const unsigned short* arow = hbase + (size_t)tA * F_ + kseg * 8;
    f32x4 acc = {};
#pragma unroll 4
    for (int fo = 0; fo < 1024; fo += 32) {
      s16x8 av = *(const s16x8*)(arow + fo);
      s16x8 bv = *(const s16x8*)(brow + fo);
      acc = __builtin_amdgcn_mfma_f32_16x16x32_bf16(av, bv, acc, 0, 0, 0);
    }
#pragma unroll
    for (int qi = 0; qi < 4; ++qi) {
      const int s = tile * 16 + kseg * 4 + qi;
      if (s < nt) {
        const int tC = bucketTok[pid * T_ + s];
        Qpart[((size_t)zf * T_ + tC) * 32 + k * 16 + rc] = acc[qi];
      }
    }
  }
}

// ---------------------------------------------------------------- down-LoRA epilogue: out += q @ B2^T (with Qpart strip-sum)
__global__ __launch_bounds__(256) void final_add_kernel(
    float* __restrict__ out, const float* __restrict__ Qpart,
    const int2* __restrict__ topi, const float* __restrict__ B2) {
  const int t = blockIdx.x, tid = threadIdx.x;
  const int2 ti = topi[t];
  float q0[16], q1[16];
#pragma unroll
  for (int r = 0; r < 16; ++r) {
    float s0 = 0.f, s1 = 0.f;
#pragma unroll
    for (int zf = 0; zf < 4; ++zf) {
      s0 += Qpart[((size_t)zf * T_ + t) * 32 + r];
      s1 += Qpart[((size_t)zf * T_ + t) * 32 + 16 + r];
    }
    q0[r] = s0; q1[r] = s1;
  }
  const float* b2e0 = B2 + (size_t)ti.x * D_ * 16;
  const float* b2e1 = B2 + (size_t)ti.y * D_ * 16;
#pragma unroll
  for (int jj = 0; jj < 4; ++jj) {
    const int d = jj * 256 + tid;
    const float* r0 = b2e0 + (size_t)d * 16;
    const float* r1 = b2e1 + (size_t)d * 16;
    float acc = out[(size_t)t * D_ + d];
#pragma unroll
    for (int r = 0; r < 16; ++r) acc += q0[r] * r0[r] + q1[r] * r1[r];
    out[(size_t)t * D_ + d] = acc;
  }
}

// ---------------------------------------------------------------- launcher
extern "C" void kernel_launch(void* const* d_in, const int* in_sizes, int n_in,
                              void* d_out, int out_size, void* d_ws, size_t ws_size,
                              hipStream_t stream) {
  (void)in_sizes; (void)n_in; (void)out_size; (void)ws_size;
  const float* x   = (const float*)d_in[0];
  const float* gw  = (const float*)d_in[1];
  const float* W1  = (const float*)d_in[2];
  const float* W3  = (const float*)d_in[3];
  const float* W2  = (const float*)d_in[4];
  const float* A1  = (const float*)d_in[5];
  const float* B1  = (const float*)d_in[6];
  const float* A3  = (const float*)d_in[7];
  const float* B3  = (const float*)d_in[8];
  const float* A2  = (const float*)d_in[9];
  const float* B2  = (const float*)d_in[10];
  float* out = (float*)d_out;
  float* logits = out + (size_t)T_ * D_;

  char* w = (char*)d_ws;
  auto alloc = [&](size_t bytes) { char* p = w; w += (bytes + 255) & ~(size_t)255; return p; };
  unsigned short* xb    = (unsigned short*)alloc((size_t)T_ * D_ * 2);
  unsigned short* Wcatb = (unsigned short*)alloc((size_t)NCAT * D_ * 2);
  unsigned short* W2b   = (unsigned short*)alloc((size_t)D_ * F_ * 2);
  unsigned short* B1b   = (unsigned short*)alloc((size_t)E_ * F_ * 16 * 2);
  unsigned short* B3b   = (unsigned short*)alloc((size_t)E_ * F_ * 16 * 2);
  unsigned short* A2r   = (unsigned short*)alloc((size_t)E_ * 16 * F_ * 2);
  unsigned short* xguP  = (unsigned short*)alloc((size_t)T_ * NCAT * 2);
  unsigned short* hsum  = (unsigned short*)alloc((size_t)T_ * F_ * 2);
  unsigned short* hk    = (unsigned short*)alloc((size_t)2 * T_ * F_ * 2);
  float* Qpart          = (float*)alloc((size_t)4 * T_ * 32 * 4);
  int* bucketTok        = (int*)alloc((size_t)64 * T_ * 4);
  int* bucketCnt        = (int*)alloc((size_t)64 * 4);
  int2* topi            = (int2*)alloc((size_t)T_ * 8);
  float2* topw          = (float2*)alloc((size_t)T_ * 8);

  conv_kernel<<<dim3(2048, 5), 256, 0, stream>>>(x, W1, W3, W2, A1, A3, B1, B3, A2,
                                                 xb, Wcatb, W2b, B1b, B3b, A2r);
  router_kernel<<<dim3(1024), 256, 0, stream>>>(x, gw, logits, topi, topw);
  bucket_kernel<<<dim3(64), 256, 0, stream>>>(topi, bucketTok, bucketCnt);
  gemm_bt<128, unsigned short><<<dim3(32 * 66), 256, 0, stream>>>(xb, Wcatb, xguP, T_, NCAT, D_, 32);
  s3a_kernel<<<dim3(16, 64, S3A_NZ), 256, 0, stream>>>(xguP, B1b, B3b, bucketTok, bucketCnt, topw, hk, hsum);
  qgemm_kernel<<<dim3(64, 2, 4), 256, 0, stream>>>(hk, A2r, bucketTok, bucketCnt, Qpart);
  gemm_bt<64, float><<<dim3(32 * 16), 256, 0, stream>>>(hsum, W2b, out, T_, D_, F_, 32);
  final_add_kernel<<<dim3(4096), 256, 0, stream>>>(out, Qpart, topi, B2);
}

// Round 5
// 366.545 us; speedup vs baseline: 1.0992x; 1.0180x over previous
//
#include <hip/hip_runtime.h>
#include <stdint.h>

#define T_ 4096
#define D_ 1024
#define F_ 4096
#define E_ 8
#define NCAT 8448  // 4096 (gate) + 4096 (up) + 256 (2*A1cat | 2*A3cat rows)
#define NTILE_MAX 320

typedef __attribute__((ext_vector_type(8))) short          s16x8;
typedef __attribute__((ext_vector_type(8))) unsigned short u16x8;
typedef __attribute__((ext_vector_type(4))) float          f32x4;

__device__ __forceinline__ unsigned short f2bf(float f) {
  unsigned u = __float_as_uint(f);
  u += 0x7fffu + ((u >> 16) & 1u);   // round-to-nearest-even
  return (unsigned short)(u >> 16);
}
__device__ __forceinline__ float b2f(unsigned short h) {
  return __uint_as_float(((unsigned)h) << 16);
}

// ---------------------------------------------------------------- convert
__device__ __forceinline__ void cvt8(const float* __restrict__ s, unsigned short* __restrict__ d) {
  float4 a = *(const float4*)s;
  float4 b = *(const float4*)(s + 4);
  u16x8 v;
  v[0] = f2bf(a.x); v[1] = f2bf(a.y); v[2] = f2bf(a.z); v[3] = f2bf(a.w);
  v[4] = f2bf(b.x); v[5] = f2bf(b.y); v[6] = f2bf(b.z); v[7] = f2bf(b.w);
  *(u16x8*)d = v;
}
__device__ __forceinline__ void cvt8s2(const float* __restrict__ s, unsigned short* __restrict__ d) {
  float4 a = *(const float4*)s;
  float4 b = *(const float4*)(s + 4);
  u16x8 v;
  v[0] = f2bf(2.f * a.x); v[1] = f2bf(2.f * a.y); v[2] = f2bf(2.f * a.z); v[3] = f2bf(2.f * a.w);
  v[4] = f2bf(2.f * b.x); v[5] = f2bf(2.f * b.y); v[6] = f2bf(2.f * b.z); v[7] = f2bf(2.f * b.w);
  *(u16x8*)d = v;
}

__global__ __launch_bounds__(256) void conv_kernel(
    const float* __restrict__ x,  const float* __restrict__ W1,
    const float* __restrict__ W3, const float* __restrict__ W2,
    const float* __restrict__ A1, const float* __restrict__ A3,
    const float* __restrict__ B1, const float* __restrict__ B3,
    const float* __restrict__ A2,
    unsigned short* __restrict__ xb,  unsigned short* __restrict__ Wcatb,
    unsigned short* __restrict__ W2b, unsigned short* __restrict__ B1b,
    unsigned short* __restrict__ B3b, unsigned short* __restrict__ A2r) {
  const int y = blockIdx.y;
  const size_t i0 = ((size_t)blockIdx.x * 256 + threadIdx.x) * 8;
  if (y == 0) { cvt8(x + i0, xb + i0); }
  else if (y == 1) { cvt8(W2 + i0, W2b + i0); }
  else if (y == 2) { cvt8(W1 + i0, Wcatb + i0); }
  else if (y == 3) { cvt8(W3 + i0, Wcatb + 4194304 + i0); }
  else {
    // small tensors, 8-wide. SCALE=2 folded into A-matrices. 229376 groups of 8.
    const size_t o8 = (size_t)blockIdx.x * 256 + threadIdx.x;
    if (o8 < 229376) {
      const size_t o = o8 * 8;
      if (o < 131072)        cvt8s2(A1 + o, Wcatb + 8388608 + o);
      else if (o < 262144)   cvt8s2(A3 + (o - 131072), Wcatb + 8388608 + o);
      else if (o < 786432)   cvt8(B1 + (o - 262144), B1b + (o - 262144));
      else if (o < 1310720)  cvt8(B3 + (o - 786432), B3b + (o - 786432));
      else                   cvt8s2(A2 + (o - 1310720), A2r + (o - 1310720)); // [E][16][F]
    }
  }
}

// ---------------------------------------------------------------- router
__global__ __launch_bounds__(256) void router_kernel(
    const float* __restrict__ x, const float* __restrict__ gw,
    float* __restrict__ logits, int2* __restrict__ topi, float2* __restrict__ topw) {
  const int wave = threadIdx.x >> 6, lane = threadIdx.x & 63;
  const int t = blockIdx.x * 4 + wave;
  const float* xr = x + (size_t)t * D_;
  float acc[E_] = {0, 0, 0, 0, 0, 0, 0, 0};
  for (int it = 0; it < 16; ++it) {
    const int d = lane + it * 64;
    const float xv = xr[d];
#pragma unroll
    for (int e = 0; e < E_; ++e) acc[e] += xv * gw[e * D_ + d];
  }
#pragma unroll
  for (int e = 0; e < E_; ++e)
#pragma unroll
    for (int m = 1; m < 64; m <<= 1) acc[e] += __shfl_xor(acc[e], m);
  if (lane == 0) {
    float m0v = acc[0]; int m0i = 0;
#pragma unroll
    for (int e = 1; e < E_; ++e) if (acc[e] > m0v) { m0v = acc[e]; m0i = e; }
    float m1v = -3.0e38f; int m1i = 0;
#pragma unroll
    for (int e = 0; e < E_; ++e) if (e != m0i && acc[e] > m1v) { m1v = acc[e]; m1i = e; }
    const float e1 = __expf(m1v - m0v);
    const float inv = 1.f / (1.f + e1);
    topi[t] = make_int2(m0i, m1i);
    topw[t] = make_float2(inv, e1 * inv);
#pragma unroll
    for (int e = 0; e < E_; ++e) logits[(size_t)t * E_ + e] = acc[e];
  }
}

// ---------------------------------------------------------------- pair buckets
__global__ __launch_bounds__(256) void bucket_kernel(
    const int2* __restrict__ topi, int* __restrict__ bucketTok, int* __restrict__ bucketCnt) {
  const int pid = blockIdx.x;
  const int e0 = pid >> 3, e1 = pid & 7;
  __shared__ int cnt;
  if (threadIdx.x == 0) cnt = 0;
  __syncthreads();
  for (int t = threadIdx.x; t < T_; t += 256) {
    const int2 ti = topi[t];
    if (ti.x == e0 && ti.y == e1) {
      const int s = atomicAdd(&cnt, 1);
      bucketTok[pid * T_ + s] = t;
    }
  }
  __syncthreads();
  if (threadIdx.x == 0) bucketCnt[pid] = cnt;
}

// ---------------------------------------------------------------- compact tile worklist (wave prefix scan)
__global__ void tilelist_kernel(const int* __restrict__ bucketCnt, int* __restrict__ tileList) {
  const int pid = threadIdx.x;  // 64 threads, 1 wave
  const int ntile = (bucketCnt[pid] + 15) >> 4;
  int scan = ntile;
#pragma unroll
  for (int m = 1; m < 64; m <<= 1) {
    const int v = __shfl_up(scan, m);
    if (pid >= m) scan += v;
  }
  const int base = scan - ntile;
  const int total = __shfl(scan, 63);
  for (int i = 0; i < ntile; ++i) tileList[base + i] = (pid << 16) | i;
  for (int i = total + pid; i < NTILE_MAX; i += 64) tileList[i] = -1;
}

// ---------------------------------------------------------------- GEMM: C[M,N] = A[M,K] @ B[N,K]^T
__device__ __forceinline__ void cstore(float* C, size_t i, float v) { C[i] = v; }
__device__ __forceinline__ void cstore(unsigned short* C, size_t i, float v) { C[i] = f2bf(v); }

#define GLL(g, l) __builtin_amdgcn_global_load_lds(                            \
    (const __attribute__((address_space(1))) void*)(g),                       \
    (__attribute__((address_space(3))) void*)(l), 16, 0, 0)

template <int BN, typename OUT_T>
__global__ __launch_bounds__(256) void gemm_bt(
    const unsigned short* __restrict__ A, const unsigned short* __restrict__ B,
    OUT_T* __restrict__ C, int M, int N, int K, int nbx) {
  constexpr int WCOL = BN / 2, NF = WCOL / 16;
  constexpr int BITER = BN / 32;                 // 16B granules per thread for B tile
  __shared__ __align__(16) char As[16384];       // 128 x 64 bf16, XOR-swizzled image
  __shared__ __align__(16) char Bs[BN * 128];
  const int tid = threadIdx.x;
  int bid = blockIdx.x;
  bid = (bid & 7) * (gridDim.x >> 3) + (bid >> 3);  // XCD swizzle (grid %8==0)
  const int bx = bid % nbx, by = bid / nbx;
  const long m0 = (long)bx * 128, n0 = (long)by * BN;

  // pre-swizzled global sources: linear LDS granule g holds source (row=g>>3, cb=(g&7)^(row&7))
  const unsigned short* asrc[4];
  const unsigned short* bsrc[BITER];
#pragma unroll
  for (int i = 0; i < 4; ++i) {
    const int g = i * 256 + tid, row = g >> 3, cb = (g & 7) ^ (row & 7);
    asrc[i] = A + (m0 + row) * (size_t)K + cb * 8;
  }
#pragma unroll
  for (int i = 0; i < BITER; ++i) {
    const int g = i * 256 + tid, row = g >> 3, cb = (g & 7) ^ (row & 7);
    bsrc[i] = B + (n0 + row) * (size_t)K + cb * 8;
  }
  const int lane = tid & 63, wave = tid >> 6;
  const int wr = wave >> 1, wc = wave & 1;
  const int wb = (tid & 192) * 16;               // wave-uniform LDS granule base (bytes)
  int aoff[4][2], boff[NF][2];
#pragma unroll
  for (int mf = 0; mf < 4; ++mf) {
    const int ra = wr * 64 + mf * 16 + (lane & 15);
#pragma unroll
    for (int ks = 0; ks < 2; ++ks) {
      const int kb = (ks * 32 + (lane >> 4) * 8) * 2;
      aoff[mf][ks] = (ra * 128 + kb) ^ ((ra & 7) << 4);
    }
  }
#pragma unroll
  for (int nf = 0; nf < NF; ++nf) {
    const int rb = wc * WCOL + nf * 16 + (lane & 15);
#pragma unroll
    for (int ks = 0; ks < 2; ++ks) {
      const int kb = (ks * 32 + (lane >> 4) * 8) * 2;
      boff[nf][ks] = (rb * 128 + kb) ^ ((rb & 7) << 4);
    }
  }
  f32x4 acc[4][NF] = {};
  const int nk = K >> 6;
  for (int kt = 0; kt < nk; ++kt) {
    __syncthreads();
#pragma unroll
    for (int i = 0; i < 4; ++i) {
      GLL(asrc[i], As + i * 4096 + wb);
      asrc[i] += 64;
    }
#pragma unroll
    for (int i = 0; i < BITER; ++i) {
      GLL(bsrc[i], Bs + i * 4096 + wb);
      bsrc[i] += 64;
    }
    __syncthreads();
#pragma unroll
    for (int ks = 0; ks < 2; ++ks) {
      s16x8 af[4], bfv[NF];
#pragma unroll
      for (int mf = 0; mf < 4; ++mf) af[mf] = *(const s16x8*)(As + aoff[mf][ks]);
#pragma unroll
      for (int nf = 0; nf < NF; ++nf) bfv[nf] = *(const s16x8*)(Bs + boff[nf][ks]);
#pragma unroll
      for (int mf = 0; mf < 4; ++mf)
#pragma unroll
        for (int nf = 0; nf < NF; ++nf)
          acc[mf][nf] = __builtin_amdgcn_mfma_f32_16x16x32_bf16(af[mf], bfv[nf], acc[mf][nf], 0, 0, 0);
    }
  }
#pragma unroll
  for (int mf = 0; mf < 4; ++mf) {
    const int row0 = (int)m0 + wr * 64 + mf * 16 + ((lane >> 4) << 2);
#pragma unroll
    for (int nf = 0; nf < NF; ++nf) {
      const long col = n0 + wc * WCOL + nf * 16 + (lane & 15);
#pragma unroll
      for (int q = 0; q < 4; ++q)
        cstore(C, (size_t)(row0 + q) * N + col, acc[mf][nf][q]);
    }
  }
}

// ---------------------------------------------------------------- fused SwiGLU + LoRA-B via MFMA
// A[t,0:16]=p1e, A[t,16:32]=p3e ; Bg=[B1;0], Bu=[0;B3] -> one MFMA pair per expert per 16x16 tile.
__global__ __launch_bounds__(256) void s3b_kernel(
    const unsigned short* __restrict__ xguP,  // [T, NCAT]
    const unsigned short* __restrict__ B1b,   // [E][F][16] bf16
    const unsigned short* __restrict__ B3b,   // [E][F][16] bf16
    const int* __restrict__ bucketTok, const int* __restrict__ bucketCnt,
    const float2* __restrict__ topw, const int* __restrict__ tileList,
    unsigned short* __restrict__ hk,          // [2][T][F] bf16 (w_k * h_k)
    unsigned short* __restrict__ hsum) {      // [T][F] bf16
  const int entry = tileList[blockIdx.x];
  if (entry < 0) return;
  const int pid = entry >> 16, z = entry & 0xffff;
  const int nt = bucketCnt[pid];
  const int e0 = pid >> 3, e1 = pid & 7;

  __shared__ int   ldsTok[16];
  __shared__ float ldsW[2][16];
  const int tid = threadIdx.x;
  if (tid < 16) {
    int s = z * 16 + tid; if (s >= nt) s = nt - 1;
    const int t = bucketTok[pid * T_ + s];
    ldsTok[tid] = t;
    const float2 w = topw[t];
    ldsW[0][tid] = w.x; ldsW[1][tid] = w.y;
  }
  __syncthreads();

  const int lane = tid & 63, wave = tid >> 6;
  const int col = lane & 15, chunk = lane >> 4;

  // A-frags: row = token ldsTok[col]; k-chunk -> p1/p3 halves (verified 16x16x32 map)
  const int at = ldsTok[col];
  const unsigned short* abase = xguP + (size_t)at * NCAT + 8192 +
                                (chunk >> 1) * 128 + (chunk & 1) * 8;
  const s16x8 afrag0 = *(const s16x8*)(abase + e0 * 16);
  const s16x8 afrag1 = *(const s16x8*)(abase + e1 * 16);

  int trow[4]; float w0r[4], w1r[4];
#pragma unroll
  for (int q = 0; q < 4; ++q) {
    trow[q] = ldsTok[chunk * 4 + q];
    w0r[q] = ldsW[0][chunk * 4 + q];
    w1r[q] = ldsW[1][chunk * 4 + q];
  }

  const int ft0 = blockIdx.y * 64 + wave * 16;   // 16 f-tiles per wave, f-quarter per blockIdx.y
  for (int i = 0; i < 16; ++i) {
    const int f = (ft0 + i) * 16 + col;
    s16x8 bg0 = {}, bu0 = {}, bg1 = {}, bu1 = {};
    if (chunk < 2) {
      bg0 = *(const s16x8*)(B1b + ((size_t)e0 * F_ + f) * 16 + chunk * 8);
      bg1 = *(const s16x8*)(B1b + ((size_t)e1 * F_ + f) * 16 + chunk * 8);
    } else {
      bu0 = *(const s16x8*)(B3b + ((size_t)e0 * F_ + f) * 16 + (chunk - 2) * 8);
      bu1 = *(const s16x8*)(B3b + ((size_t)e1 * F_ + f) * 16 + (chunk - 2) * 8);
    }
    f32x4 accg0 = {}, accu0 = {}, accg1 = {}, accu1 = {};
    accg0 = __builtin_amdgcn_mfma_f32_16x16x32_bf16(afrag0, bg0, accg0, 0, 0, 0);
    accu0 = __builtin_amdgcn_mfma_f32_16x16x32_bf16(afrag0, bu0, accu0, 0, 0, 0);
    accg1 = __builtin_amdgcn_mfma_f32_16x16x32_bf16(afrag1, bg1, accg1, 0, 0, 0);
    accu1 = __builtin_amdgcn_mfma_f32_16x16x32_bf16(afrag1, bu1, accu1, 0, 0, 0);
#pragma unroll
    for (int q = 0; q < 4; ++q) {
      const int t = trow[q];
      const unsigned short* xr = xguP + (size_t)t * NCAT + f;
      const float xg = b2f(xr[0]);
      const float xu = b2f(xr[4096]);
      const float g0 = xg + accg0[q], u0 = xu + accu0[q];
      const float g1 = xg + accg1[q], u1 = xu + accu1[q];
      const float h0 = (g0 / (1.f + __expf(-g0))) * u0;   // exact round-3 silu
      const float h1 = (g1 / (1.f + __expf(-g1))) * u1;
      const float hw0 = w0r[q] * h0, hw1 = w1r[q] * h1;
      hk[(size_t)t * F_ + f]                   = f2bf(hw0);
      hk[(size_t)T_ * F_ + (size_t)t * F_ + f] = f2bf(hw1);
      hsum[(size_t)t * F_ + f]                 = f2bf(hw0 + hw1);
    }
  }
}

// ---------------------------------------------------------------- q = hw_k @ (2*A2[e])^T  via gather-MFMA, F split 4-way
__global__ __launch_bounds__(256) void qgemm_kernel(
    const unsigned short* __restrict__ hk, const unsigned short* __restrict__ A2r,
    const int* __restrict__ bucketTok, const int* __restrict__ bucketCnt,
    float* __restrict__ Qpart) {              // [4][T][32]
  const int pid = blockIdx.x, k = blockIdx.y, zf = blockIdx.z;
  const int nt = bucketCnt[pid];
  if (nt == 0) return;
  const int e = k ? (pid & 7) : (pid >> 3);
  const int lane = threadIdx.x & 63, wave = threadIdx.x >> 6;
  const int rc = lane & 15, kseg = lane >> 4;
  const int f0 = zf * 1024;
  const unsigned short* brow = A2r + ((size_t)e * 16 + rc) * F_ + f0 + kseg * 8;
  const unsigned short* hbase = hk + (size_t)k * T_ * F_ + f0;
  const int ntile = (nt + 15) >> 4;
  for (int tile = wave; tile < ntile; tile += 4) {
    const int sA = tile * 16 + rc;
    const int tA = bucketTok[pid * T_ + (sA < nt ? sA : nt - 1)];
    const unsigned short* arow = hbase + (size_t)tA * F_ + kseg * 8;
    f32x4 acc = {};
#pragma unroll 4
    for (int fo = 0; fo < 1024; fo += 32) {
      s16x8 av = *(const s16x8*)(arow + fo);
      s16x8 bv = *(const s16x8*)(brow + fo);
      acc = __builtin_amdgcn_mfma_f32_16x16x32_bf16(av, bv, acc, 0, 0, 0);
    }
#pragma unroll
    for (int qi = 0; qi < 4; ++qi) {
      const int s = tile * 16 + kseg * 4 + qi;
      if (s < nt) {
        const int tC = bucketTok[pid * T_ + s];
        Qpart[((size_t)zf * T_ + tC) * 32 + k * 16 + rc] = acc[qi];
      }
    }
  }
}

// ---------------------------------------------------------------- down-LoRA epilogue: out += q @ B2^T (with Qpart strip-sum)
__global__ __launch_bounds__(256) void final_add_kernel(
    float* __restrict__ out, const float* __restrict__ Qpart,
    const int2* __restrict__ topi, const float* __restrict__ B2) {
  const int t = blockIdx.x, tid = threadIdx.x;
  const int2 ti = topi[t];
  float q0[16], q1[16];
#pragma unroll
  for (int r = 0; r < 16; ++r) {
    float s0 = 0.f, s1 = 0.f;
#pragma unroll
    for (int zf = 0; zf < 4; ++zf) {
      s0 += Qpart[((size_t)zf * T_ + t) * 32 + r];
      s1 += Qpart[((size_t)zf * T_ + t) * 32 + 16 + r];
    }
    q0[r] = s0; q1[r] = s1;
  }
  const float* b2e0 = B2 + (size_t)ti.x * D_ * 16;
  const float* b2e1 = B2 + (size_t)ti.y * D_ * 16;
#pragma unroll
  for (int jj = 0; jj < 4; ++jj) {
    const int d = jj * 256 + tid;
    const float* r0 = b2e0 + (size_t)d * 16;
    const float* r1 = b2e1 + (size_t)d * 16;
    float acc = out[(size_t)t * D_ + d];
#pragma unroll
    for (int r = 0; r < 16; ++r) acc += q0[r] * r0[r] + q1[r] * r1[r];
    out[(size_t)t * D_ + d] = acc;
  }
}

// ---------------------------------------------------------------- launcher
extern "C" void kernel_launch(void* const* d_in, const int* in_sizes, int n_in,
                              void* d_out, int out_size, void* d_ws, size_t ws_size,
                              hipStream_t stream) {
  (void)in_sizes; (void)n_in; (void)out_size; (void)ws_size;
  const float* x   = (const float*)d_in[0];
  const float* gw  = (const float*)d_in[1];
  const float* W1  = (const float*)d_in[2];
  const float* W3  = (const float*)d_in[3];
  const float* W2  = (const float*)d_in[4];
  const float* A1  = (const float*)d_in[5];
  const float* B1  = (const float*)d_in[6];
  const float* A3  = (const float*)d_in[7];
  const float* B3  = (const float*)d_in[8];
  const float* A2  = (const float*)d_in[9];
  const float* B2  = (const float*)d_in[10];
  float* out = (float*)d_out;
  float* logits = out + (size_t)T_ * D_;

  char* w = (char*)d_ws;
  auto alloc = [&](size_t bytes) { char* p = w; w += (bytes + 255) & ~(size_t)255; return p; };
  unsigned short* xb    = (unsigned short*)alloc((size_t)T_ * D_ * 2);
  unsigned short* Wcatb = (unsigned short*)alloc((size_t)NCAT * D_ * 2);
  unsigned short* W2b   = (unsigned short*)alloc((size_t)D_ * F_ * 2);
  unsigned short* B1b   = (unsigned short*)alloc((size_t)E_ * F_ * 16 * 2);
  unsigned short* B3b   = (unsigned short*)alloc((size_t)E_ * F_ * 16 * 2);
  unsigned short* A2r   = (unsigned short*)alloc((size_t)E_ * 16 * F_ * 2);
  unsigned short* xguP  = (unsigned short*)alloc((size_t)T_ * NCAT * 2);
  unsigned short* hsum  = (unsigned short*)alloc((size_t)T_ * F_ * 2);
  unsigned short* hk    = (unsigned short*)alloc((size_t)2 * T_ * F_ * 2);
  float* Qpart          = (float*)alloc((size_t)4 * T_ * 32 * 4);
  int* bucketTok        = (int*)alloc((size_t)64 * T_ * 4);
  int* bucketCnt        = (int*)alloc((size_t)64 * 4);
  int* tileList         = (int*)alloc((size_t)NTILE_MAX * 4);
  int2* topi            = (int2*)alloc((size_t)T_ * 8);
  float2* topw          = (float2*)alloc((size_t)T_ * 8);

  conv_kernel<<<dim3(2048, 5), 256, 0, stream>>>(x, W1, W3, W2, A1, A3, B1, B3, A2,
                                                 xb, Wcatb, W2b, B1b, B3b, A2r);
  router_kernel<<<dim3(1024), 256, 0, stream>>>(x, gw, logits, topi, topw);
  bucket_kernel<<<dim3(64), 256, 0, stream>>>(topi, bucketTok, bucketCnt);
  tilelist_kernel<<<dim3(1), 64, 0, stream>>>(bucketCnt, tileList);
  gemm_bt<128, unsigned short><<<dim3(32 * 66), 256, 0, stream>>>(xb, Wcatb, xguP, T_, NCAT, D_, 32);
  s3b_kernel<<<dim3(NTILE_MAX, 4), 256, 0, stream>>>(xguP, B1b, B3b, bucketTok, bucketCnt,
                                                     topw, tileList, hk, hsum);
  qgemm_kernel<<<dim3(64, 2, 4), 256, 0, stream>>>(hk, A2r, bucketTok, bucketCnt, Qpart);
  gemm_bt<64, float><<<dim3(32 * 16), 256, 0, stream>>>(hsum, W2b, out, T_, D_, F_, 32);
  final_add_kernel<<<dim3(4096), 256, 0, stream>>>(out, Qpart, topi, B2);
}

// Round 7
// 350.377 us; speedup vs baseline: 1.1500x; 1.0461x over previous
//
#include <hip/hip_runtime.h>
#include <stdint.h>

#define T_ 4096
#define D_ 1024
#define F_ 4096
#define E_ 8
#define NCAT 8448  // 4096 (gate) + 4096 (up) + 256 (2*A1cat | 2*A3cat rows)
#define NTILE_MAX 320

typedef __attribute__((ext_vector_type(8))) short          s16x8;
typedef __attribute__((ext_vector_type(8))) unsigned short u16x8;
typedef __attribute__((ext_vector_type(4))) float          f32x4;

__device__ __forceinline__ unsigned short f2bf(float f) {
  unsigned u = __float_as_uint(f);
  u += 0x7fffu + ((u >> 16) & 1u);   // round-to-nearest-even
  return (unsigned short)(u >> 16);
}
__device__ __forceinline__ float b2f(unsigned short h) {
  return __uint_as_float(((unsigned)h) << 16);
}

// ---------------------------------------------------------------- convert
__device__ __forceinline__ void cvt8(const float* __restrict__ s, unsigned short* __restrict__ d) {
  float4 a = *(const float4*)s;
  float4 b = *(const float4*)(s + 4);
  u16x8 v;
  v[0] = f2bf(a.x); v[1] = f2bf(a.y); v[2] = f2bf(a.z); v[3] = f2bf(a.w);
  v[4] = f2bf(b.x); v[5] = f2bf(b.y); v[6] = f2bf(b.z); v[7] = f2bf(b.w);
  *(u16x8*)d = v;
}
__device__ __forceinline__ void cvt8s2(const float* __restrict__ s, unsigned short* __restrict__ d) {
  float4 a = *(const float4*)s;
  float4 b = *(const float4*)(s + 4);
  u16x8 v;
  v[0] = f2bf(2.f * a.x); v[1] = f2bf(2.f * a.y); v[2] = f2bf(2.f * a.z); v[3] = f2bf(2.f * a.w);
  v[4] = f2bf(2.f * b.x); v[5] = f2bf(2.f * b.y); v[6] = f2bf(2.f * b.z); v[7] = f2bf(2.f * b.w);
  *(u16x8*)d = v;
}

__global__ __launch_bounds__(256) void conv_kernel(
    const float* __restrict__ x,  const float* __restrict__ W1,
    const float* __restrict__ W3, const float* __restrict__ W2,
    const float* __restrict__ A1, const float* __restrict__ A3,
    const float* __restrict__ B1, const float* __restrict__ B3,
    const float* __restrict__ A2,
    unsigned short* __restrict__ xb,  unsigned short* __restrict__ Wcatb,
    unsigned short* __restrict__ W2b, unsigned short* __restrict__ B1b,
    unsigned short* __restrict__ B3b, unsigned short* __restrict__ A2r) {
  const int y = blockIdx.y;
  const size_t i0 = ((size_t)blockIdx.x * 256 + threadIdx.x) * 8;
  if (y == 0) { cvt8(x + i0, xb + i0); }
  else if (y == 1) { cvt8(W2 + i0, W2b + i0); }
  else if (y == 2) { cvt8(W1 + i0, Wcatb + i0); }
  else if (y == 3) { cvt8(W3 + i0, Wcatb + 4194304 + i0); }
  else {
    // small tensors, 8-wide. SCALE=2 folded into A-matrices. 229376 groups of 8.
    const size_t o8 = (size_t)blockIdx.x * 256 + threadIdx.x;
    if (o8 < 229376) {
      const size_t o = o8 * 8;
      if (o < 131072)        cvt8s2(A1 + o, Wcatb + 8388608 + o);
      else if (o < 262144)   cvt8s2(A3 + (o - 131072), Wcatb + 8388608 + o);
      else if (o < 786432)   cvt8(B1 + (o - 262144), B1b + (o - 262144));
      else if (o < 1310720)  cvt8(B3 + (o - 786432), B3b + (o - 786432));
      else                   cvt8s2(A2 + (o - 1310720), A2r + (o - 1310720)); // [E][16][F]
    }
  }
}

// ---------------------------------------------------------------- router
__global__ __launch_bounds__(256) void router_kernel(
    const float* __restrict__ x, const float* __restrict__ gw,
    float* __restrict__ logits, int2* __restrict__ topi, float2* __restrict__ topw) {
  const int wave = threadIdx.x >> 6, lane = threadIdx.x & 63;
  const int t = blockIdx.x * 4 + wave;
  const float* xr = x + (size_t)t * D_;
  float acc[E_] = {0, 0, 0, 0, 0, 0, 0, 0};
  for (int it = 0; it < 16; ++it) {
    const int d = lane + it * 64;
    const float xv = xr[d];
#pragma unroll
    for (int e = 0; e < E_; ++e) acc[e] += xv * gw[e * D_ + d];
  }
#pragma unroll
  for (int e = 0; e < E_; ++e)
#pragma unroll
    for (int m = 1; m < 64; m <<= 1) acc[e] += __shfl_xor(acc[e], m);
  if (lane == 0) {
    float m0v = acc[0]; int m0i = 0;
#pragma unroll
    for (int e = 1; e < E_; ++e) if (acc[e] > m0v) { m0v = acc[e]; m0i = e; }
    float m1v = -3.0e38f; int m1i = 0;
#pragma unroll
    for (int e = 0; e < E_; ++e) if (e != m0i && acc[e] > m1v) { m1v = acc[e]; m1i = e; }
    const float e1 = __expf(m1v - m0v);
    const float inv = 1.f / (1.f + e1);
    topi[t] = make_int2(m0i, m1i);
    topw[t] = make_float2(inv, e1 * inv);
#pragma unroll
    for (int e = 0; e < E_; ++e) logits[(size_t)t * E_ + e] = acc[e];
  }
}

// ---------------------------------------------------------------- pair buckets
__global__ __launch_bounds__(256) void bucket_kernel(
    const int2* __restrict__ topi, int* __restrict__ bucketTok, int* __restrict__ bucketCnt) {
  const int pid = blockIdx.x;
  const int e0 = pid >> 3, e1 = pid & 7;
  __shared__ int cnt;
  if (threadIdx.x == 0) cnt = 0;
  __syncthreads();
  for (int t = threadIdx.x; t < T_; t += 256) {
    const int2 ti = topi[t];
    if (ti.x == e0 && ti.y == e1) {
      const int s = atomicAdd(&cnt, 1);
      bucketTok[pid * T_ + s] = t;
    }
  }
  __syncthreads();
  if (threadIdx.x == 0) bucketCnt[pid] = cnt;
}

// ---------------------------------------------------------------- compact tile worklist (wave prefix scan)
__global__ void tilelist_kernel(const int* __restrict__ bucketCnt, int* __restrict__ tileList) {
  const int pid = threadIdx.x;  // 64 threads, 1 wave
  const int ntile = (bucketCnt[pid] + 15) >> 4;
  int scan = ntile;
#pragma unroll
  for (int m = 1; m < 64; m <<= 1) {
    const int v = __shfl_up(scan, m);
    if (pid >= m) scan += v;
  }
  const int base = scan - ntile;
  const int total = __shfl(scan, 63);
  for (int i = 0; i < ntile; ++i) tileList[base + i] = (pid << 16) | i;
  for (int i = total + pid; i < NTILE_MAX; i += 64) tileList[i] = -1;
}

// ---------------------------------------------------------------- GEMM: C[M,N] = A[M,K] @ B[N,K]^T
// 2-phase double-buffered global_load_lds pipeline; optional K-split via blockIdx.z.
__device__ __forceinline__ void cstore(float* C, size_t i, float v) { C[i] = v; }
__device__ __forceinline__ void cstore(unsigned short* C, size_t i, float v) { C[i] = f2bf(v); }

#define GLL(g, l) __builtin_amdgcn_global_load_lds(                            \
    (const __attribute__((address_space(1))) void*)(g),                       \
    (__attribute__((address_space(3))) void*)(l), 16, 0, 0)

template <int BN, typename OUT_T>
__global__ __launch_bounds__(256) void gemm_bt(
    const unsigned short* __restrict__ A, const unsigned short* __restrict__ B,
    OUT_T* __restrict__ C, int M, int N, int Kstride, int ksub, int nbx) {
  constexpr int WCOL = BN / 2, NF = WCOL / 16;
  constexpr int BITER = BN / 32;                 // 16B granules per thread for B tile
  __shared__ __align__(16) char As[2 * 16384];   // 2 x (128 x 64 bf16), XOR-swizzled image
  __shared__ __align__(16) char Bs[2 * BN * 128];
  const int tid = threadIdx.x;
  int bid = blockIdx.x;
  bid = (bid & 7) * (gridDim.x >> 3) + (bid >> 3);  // XCD swizzle (grid %8==0)
  const int bx = bid % nbx, by = bid / nbx;
  const long m0 = (long)bx * 128, n0 = (long)by * BN;
  const int k0 = blockIdx.z * ksub;
  C += (size_t)blockIdx.z * M * N;               // K-split partial strip (z=0 only if no split)

  // pre-swizzled global sources: linear LDS granule g holds source (row=g>>3, cb=(g&7)^(row&7))
  const unsigned short* asrc[4];
  const unsigned short* bsrc[BITER];
#pragma unroll
  for (int i = 0; i < 4; ++i) {
    const int g = i * 256 + tid, row = g >> 3, cb = (g & 7) ^ (row & 7);
    asrc[i] = A + (m0 + row) * (size_t)Kstride + k0 + cb * 8;
  }
#pragma unroll
  for (int i = 0; i < BITER; ++i) {
    const int g = i * 256 + tid, row = g >> 3, cb = (g & 7) ^ (row & 7);
    bsrc[i] = B + (n0 + row) * (size_t)Kstride + k0 + cb * 8;
  }
  const int lane = tid & 63, wave = tid >> 6;
  const int wr = wave >> 1, wc = wave & 1;
  const int wb = (tid & 192) * 16;               // wave-uniform LDS granule base (bytes)
  int aoff[4][2], boff[NF][2];
#pragma unroll
  for (int mf = 0; mf < 4; ++mf) {
    const int ra = wr * 64 + mf * 16 + (lane & 15);
#pragma unroll
    for (int ks = 0; ks < 2; ++ks) {
      const int kb = (ks * 32 + (lane >> 4) * 8) * 2;
      aoff[mf][ks] = (ra * 128 + kb) ^ ((ra & 7) << 4);
    }
  }
#pragma unroll
  for (int nf = 0; nf < NF; ++nf) {
    const int rb = wc * WCOL + nf * 16 + (lane & 15);
#pragma unroll
    for (int ks = 0; ks < 2; ++ks) {
      const int kb = (ks * 32 + (lane >> 4) * 8) * 2;
      boff[nf][ks] = (rb * 128 + kb) ^ ((rb & 7) << 4);
    }
  }

  auto STAGE = [&](int buf, int kt) {
    const size_t ko = (size_t)kt * 64;
#pragma unroll
    for (int i = 0; i < 4; ++i) GLL(asrc[i] + ko, As + buf * 16384 + i * 4096 + wb);
#pragma unroll
    for (int i = 0; i < BITER; ++i) GLL(bsrc[i] + ko, Bs + buf * (BN * 128) + i * 4096 + wb);
  };

  f32x4 acc[4][NF] = {};
  const int nk = ksub >> 6;
  int cur = 0;
  STAGE(0, 0);
  asm volatile("s_waitcnt vmcnt(0)" ::: "memory");
  __builtin_amdgcn_s_barrier();
  for (int kt = 0; kt < nk; ++kt) {
    if (kt + 1 < nk) STAGE(cur ^ 1, kt + 1);     // issue next-tile loads; stay in flight
    const char* Ab = As + cur * 16384;
    const char* Bb = Bs + cur * (BN * 128);
#pragma unroll
    for (int ks = 0; ks < 2; ++ks) {
      s16x8 af[4], bfv[NF];
#pragma unroll
      for (int mf = 0; mf < 4; ++mf) af[mf] = *(const s16x8*)(Ab + aoff[mf][ks]);
#pragma unroll
      for (int nf = 0; nf < NF; ++nf) bfv[nf] = *(const s16x8*)(Bb + boff[nf][ks]);
#pragma unroll
      for (int mf = 0; mf < 4; ++mf)
#pragma unroll
        for (int nf = 0; nf < NF; ++nf)
          acc[mf][nf] = __builtin_amdgcn_mfma_f32_16x16x32_bf16(af[mf], bfv[nf], acc[mf][nf], 0, 0, 0);
    }
    asm volatile("s_waitcnt vmcnt(0)" ::: "memory");  // next tile landed
    __builtin_amdgcn_s_barrier();                     // all waves done reading cur
    cur ^= 1;
  }
#pragma unroll
  for (int mf = 0; mf < 4; ++mf) {
    const int row0 = (int)m0 + wr * 64 + mf * 16 + ((lane >> 4) << 2);
#pragma unroll
    for (int nf = 0; nf < NF; ++nf) {
      const long col = n0 + wc * WCOL + nf * 16 + (lane & 15);
#pragma unroll
      for (int q = 0; q < 4; ++q)
        cstore(C, (size_t)(row0 + q) * N + col, acc[mf][nf][q]);
    }
  }
}

// ---------------------------------------------------------------- fused SwiGLU + LoRA-B via MFMA
// A[t,0:16]=p1e, A[t,16:32]=p3e ; Bg=[B1;0], Bu=[0;B3] -> one MFMA pair per expert per 16x16 tile.
__global__ __launch_bounds__(256) void s3b_kernel(
    const unsigned short* __restrict__ xguP,  // [T, NCAT]
    const unsigned short* __restrict__ B1b,   // [E][F][16] bf16
    const unsigned short* __restrict__ B3b,   // [E][F][16] bf16
    const int* __restrict__ bucketTok, const int* __restrict__ bucketCnt,
    const float2* __restrict__ topw, const int* __restrict__ tileList,
    unsigned short* __restrict__ hk,          // [2][T][F] bf16 (w_k * h_k)
    unsigned short* __restrict__ hsum) {      // [T][F] bf16
  const int entry = tileList[blockIdx.x];
  if (entry < 0) return;
  const int pid = entry >> 16, z = entry & 0xffff;
  const int nt = bucketCnt[pid];
  const int e0 = pid >> 3, e1 = pid & 7;

  __shared__ int   ldsTok[16];
  __shared__ float ldsW[2][16];
  const int tid = threadIdx.x;
  if (tid < 16) {
    int s = z * 16 + tid; if (s >= nt) s = nt - 1;
    const int t = bucketTok[pid * T_ + s];
    ldsTok[tid] = t;
    const float2 w = topw[t];
    ldsW[0][tid] = w.x; ldsW[1][tid] = w.y;
  }
  __syncthreads();

  const int lane = tid & 63, wave = tid >> 6;
  const int col = lane & 15, chunk = lane >> 4;

  // A-frags: row = token ldsTok[col]; k-chunk -> p1/p3 halves (verified 16x16x32 map)
  const int at = ldsTok[col];
  const unsigned short* abase = xguP + (size_t)at * NCAT + 8192 +
                                (chunk >> 1) * 128 + (chunk & 1) * 8;
  const s16x8 afrag0 = *(const s16x8*)(abase + e0 * 16);
  const s16x8 afrag1 = *(const s16x8*)(abase + e1 * 16);

  int trow[4]; float w0r[4], w1r[4];
#pragma unroll
  for (int q = 0; q < 4; ++q) {
    trow[q] = ldsTok[chunk * 4 + q];
    w0r[q] = ldsW[0][chunk * 4 + q];
    w1r[q] = ldsW[1][chunk * 4 + q];
  }

  const int ft0 = blockIdx.y * 64 + wave * 16;   // 16 f-tiles per wave, f-quarter per blockIdx.y
  for (int i = 0; i < 16; ++i) {
    const int f = (ft0 + i) * 16 + col;
    s16x8 bg0 = {}, bu0 = {}, bg1 = {}, bu1 = {};
    if (chunk < 2) {
      bg0 = *(const s16x8*)(B1b + ((size_t)e0 * F_ + f) * 16 + chunk * 8);
      bg1 = *(const s16x8*)(B1b + ((size_t)e1 * F_ + f) * 16 + chunk * 8);
    } else {
      bu0 = *(const s16x8*)(B3b + ((size_t)e0 * F_ + f) * 16 + (chunk - 2) * 8);
      bu1 = *(const s16x8*)(B3b + ((size_t)e1 * F_ + f) * 16 + (chunk - 2) * 8);
    }
    f32x4 accg0 = {}, accu0 = {}, accg1 = {}, accu1 = {};
    accg0 = __builtin_amdgcn_mfma_f32_16x16x32_bf16(afrag0, bg0, accg0, 0, 0, 0);
    accu0 = __builtin_amdgcn_mfma_f32_16x16x32_bf16(afrag0, bu0, accu0, 0, 0, 0);
    accg1 = __builtin_amdgcn_mfma_f32_16x16x32_bf16(afrag1, bg1, accg1, 0, 0, 0);
    accu1 = __builtin_amdgcn_mfma_f32_16x16x32_bf16(afrag1, bu1, accu1, 0, 0, 0);
#pragma unroll
    for (int q = 0; q < 4; ++q) {
      const int t = trow[q];
      const unsigned short* xr = xguP + (size_t)t * NCAT + f;
      const float xg = b2f(xr[0]);
      const float xu = b2f(xr[4096]);
      const float g0 = xg + accg0[q], u0 = xu + accu0[q];
      const float g1 = xg + accg1[q], u1 = xu + accu1[q];
      const float h0 = (g0 / (1.f + __expf(-g0))) * u0;   // exact round-3 silu
      const float h1 = (g1 / (1.f + __expf(-g1))) * u1;
      const float hw0 = w0r[q] * h0, hw1 = w1r[q] * h1;
      hk[(size_t)t * F_ + f]                   = f2bf(hw0);
      hk[(size_t)T_ * F_ + (size_t)t * F_ + f] = f2bf(hw1);
      hsum[(size_t)t * F_ + f]                 = f2bf(hw0 + hw1);
    }
  }
}

// ---------------------------------------------------------------- q = hw_k @ (2*A2[e])^T  via gather-MFMA, F split 4-way
__global__ __launch_bounds__(256) void qgemm_kernel(
    const unsigned short* __restrict__ hk, const unsigned short* __restrict__ A2r,
    const int* __restrict__ bucketTok, const int* __restrict__ bucketCnt,
    float* __restrict__ Qpart) {              // [4][T][32]
  const int pid = blockIdx.x, k = blockIdx.y, zf = blockIdx.z;
  const int nt = bucketCnt[pid];
  if (nt == 0) return;
  const int e = k ? (pid & 7) : (pid >> 3);
  const int lane = threadIdx.x & 63, wave = threadIdx.x >> 6;
  const int rc = lane & 15, kseg = lane >> 4;
  const int f0 = zf * 1024;
  const unsigned short* brow = A2r + ((size_t)e * 16 + rc) * F_ + f0 + kseg * 8;
  const unsigned short* hbase = hk + (size_t)k * T_ * F_ + f0;
  const int ntile = (nt + 15) >> 4;
  for (int tile = wave; tile < ntile; tile += 4) {
    const int sA = tile * 16 + rc;
    const int tA = bucketTok[pid * T_ + (sA < nt ? sA : nt - 1)];
    const unsigned short* arow = hbase + (size_t)tA * F_ + kseg * 8;
    f32x4 acc = {};
#pragma unroll 4
    for (int fo = 0; fo < 1024; fo += 32) {
      s16x8 av = *(const s16x8*)(arow + fo);
      s16x8 bv = *(const s16x8*)(brow + fo);
      acc = __builtin_amdgcn_mfma_f32_16x16x32_bf16(av, bv, acc, 0, 0, 0);
    }
#pragma unroll
    for (int qi = 0; qi < 4; ++qi) {
      const int s = tile * 16 + kseg * 4 + qi;
      if (s < nt) {
        const int tC = bucketTok[pid * T_ + s];
        Qpart[((size_t)zf * T_ + tC) * 32 + k * 16 + rc] = acc[qi];
      }
    }
  }
}

// ---------------------------------------------------------------- final: out = sum_z Opart[z] + q @ B2^T
__global__ __launch_bounds__(256) void final_add_kernel(
    float* __restrict__ out, const float* __restrict__ Opart,
    const float* __restrict__ Qpart,
    const int2* __restrict__ topi, const float* __restrict__ B2) {
  const int t = blockIdx.x, tid = threadIdx.x;
  const int2 ti = topi[t];
  float q0[16], q1[16];
#pragma unroll
  for (int r = 0; r < 16; ++r) {
    float s0 = 0.f, s1 = 0.f;
#pragma unroll
    for (int zf = 0; zf < 4; ++zf) {
      s0 += Qpart[((size_t)zf * T_ + t) * 32 + r];
      s1 += Qpart[((size_t)zf * T_ + t) * 32 + 16 + r];
    }
    q0[r] = s0; q1[r] = s1;
  }
  const float* b2e0 = B2 + (size_t)ti.x * D_ * 16;
  const float* b2e1 = B2 + (size_t)ti.y * D_ * 16;
#pragma unroll
  for (int jj = 0; jj < 4; ++jj) {
    const int d = jj * 256 + tid;
    const size_t od = (size_t)t * D_ + d;
    float acc = Opart[od] + Opart[(size_t)T_ * D_ + od] +
                Opart[(size_t)2 * T_ * D_ + od] + Opart[(size_t)3 * T_ * D_ + od];
    const float* r0 = b2e0 + (size_t)d * 16;
    const float* r1 = b2e1 + (size_t)d * 16;
#pragma unroll
    for (int r = 0; r < 16; ++r) acc += q0[r] * r0[r] + q1[r] * r1[r];
    out[od] = acc;
  }
}

// ---------------------------------------------------------------- launcher
extern "C" void kernel_launch(void* const* d_in, const int* in_sizes, int n_in,
                              void* d_out, int out_size, void* d_ws, size_t ws_size,
                              hipStream_t stream) {
  (void)in_sizes; (void)n_in; (void)out_size; (void)ws_size;
  const float* x   = (const float*)d_in[0];
  const float* gw  = (const float*)d_in[1];
  const float* W1  = (const float*)d_in[2];
  const float* W3  = (const float*)d_in[3];
  const float* W2  = (const float*)d_in[4];
  const float* A1  = (const float*)d_in[5];
  const float* B1  = (const float*)d_in[6];
  const float* A3  = (const float*)d_in[7];
  const float* B3  = (const float*)d_in[8];
  const float* A2  = (const float*)d_in[9];
  const float* B2  = (const float*)d_in[10];
  float* out = (float*)d_out;
  float* logits = out + (size_t)T_ * D_;

  char* w = (char*)d_ws;
  auto alloc = [&](size_t bytes) { char* p = w; w += (bytes + 255) & ~(size_t)255; return p; };
  unsigned short* xb    = (unsigned short*)alloc((size_t)T_ * D_ * 2);
  unsigned short* Wcatb = (unsigned short*)alloc((size_t)NCAT * D_ * 2);
  unsigned short* W2b   = (unsigned short*)alloc((size_t)D_ * F_ * 2);
  unsigned short* B1b   = (unsigned short*)alloc((size_t)E_ * F_ * 16 * 2);
  unsigned short* B3b   = (unsigned short*)alloc((size_t)E_ * F_ * 16 * 2);
  unsigned short* A2r   = (unsigned short*)alloc((size_t)E_ * 16 * F_ * 2);
  unsigned short* xguP  = (unsigned short*)alloc((size_t)T_ * NCAT * 2);  // 69.2 MB
  unsigned short* hsum  = (unsigned short*)alloc((size_t)T_ * F_ * 2);
  unsigned short* hk    = (unsigned short*)alloc((size_t)2 * T_ * F_ * 2);
  float* Qpart          = (float*)alloc((size_t)4 * T_ * 32 * 4);
  int* bucketTok        = (int*)alloc((size_t)64 * T_ * 4);
  int* bucketCnt        = (int*)alloc((size_t)64 * 4);
  int* tileList         = (int*)alloc((size_t)NTILE_MAX * 4);
  int2* topi            = (int2*)alloc((size_t)T_ * 8);
  float2* topw          = (float2*)alloc((size_t)T_ * 8);
  // Opart (4*T*D*4 = 67.1 MB) ALIASES xguP (69.2 MB): xguP is dead after s3b_kernel,
  // and stream order s3b -> qgemm -> gemm2 -> final_add makes the reuse race-free.
  float* Opart          = (float*)xguP;

  conv_kernel<<<dim3(2048, 5), 256, 0, stream>>>(x, W1, W3, W2, A1, A3, B1, B3, A2,
                                                 xb, Wcatb, W2b, B1b, B3b, A2r);
  router_kernel<<<dim3(1024), 256, 0, stream>>>(x, gw, logits, topi, topw);
  bucket_kernel<<<dim3(64), 256, 0, stream>>>(topi, bucketTok, bucketCnt);
  tilelist_kernel<<<dim3(1), 64, 0, stream>>>(bucketCnt, tileList);
  // gemm1: xguP = xb @ Wcat^T   [4096 x 8448], K=1024
  gemm_bt<128, unsigned short><<<dim3(32 * 66, 1, 1), 256, 0, stream>>>(
      xb, Wcatb, xguP, T_, NCAT, 1024, 1024, 32);
  s3b_kernel<<<dim3(NTILE_MAX, 4), 256, 0, stream>>>(xguP, B1b, B3b, bucketTok, bucketCnt,
                                                     topw, tileList, hk, hsum);
  qgemm_kernel<<<dim3(64, 2, 4), 256, 0, stream>>>(hk, A2r, bucketTok, bucketCnt, Qpart);
  // gemm2: Opart[z] = hsum @ W2^T (K-chunk z)   [4096 x 1024], K=4096 split 4x1024
  gemm_bt<128, float><<<dim3(32 * 8, 1, 4), 256, 0, stream>>>(
      hsum, W2b, Opart, T_, D_, 4096, 1024, 32);
  final_add_kernel<<<dim3(4096), 256, 0, stream>>>(out, Opart, Qpart, topi, B2);
}